// Round 2
// baseline (313.691 us; speedup 1.0000x reference)
//
#include <hip/hip_runtime.h>
#include <hip/hip_bf16.h>

typedef __attribute__((ext_vector_type(8))) short short8;
typedef __attribute__((ext_vector_type(4))) float floatx4;

#define REG_CAP 106496   // per-shard pair-region capacity (~100K expected + slack)

__device__ __forceinline__ float bf_lo(unsigned int u) { return __uint_as_float(u << 16); }
__device__ __forceinline__ float bf_hi(unsigned int u) { return __uint_as_float(u & 0xffff0000u); }

__device__ __forceinline__ unsigned short f2bf_rne(float f) {
    unsigned u = __float_as_uint(f);
    unsigned rb = (u >> 16) & 1u;
    u += 0x7fffu + rb;
    return (unsigned short)(u >> 16);
}
__device__ __forceinline__ unsigned int pack_bf2(float x, float y) {
    return (unsigned int)f2bf_rne(x) | ((unsigned int)f2bf_rne(y) << 16);
}

__device__ __forceinline__ void acc4(unsigned long long v, float& f0, float& f1, float& f2, float& f3) {
    unsigned ua = (unsigned)v, ub = (unsigned)(v >> 32);
    f0 += bf_lo(ua); f1 += bf_hi(ua); f2 += bf_lo(ub); f3 += bf_hi(ub);
}
__device__ __forceinline__ void acc8(ulonglong2 v, float& f0, float& f1, float& f2, float& f3,
                                     float& f4, float& f5, float& f6, float& f7) {
    unsigned ua0 = (unsigned)v.x, ub0 = (unsigned)(v.x >> 32);
    unsigned ua1 = (unsigned)v.y, ub1 = (unsigned)(v.y >> 32);
    f0 += bf_lo(ua0); f1 += bf_hi(ua0); f2 += bf_lo(ub0); f3 += bf_hi(ub0);
    f4 += bf_lo(ua1); f5 += bf_hi(ua1); f6 += bf_lo(ub1); f7 += bf_hi(ub1);
}

// ---------------- prep: fused edge-binning + deg-count (blocks [0,nBin)) + convert/pack (rest) ----------------

__global__ __launch_bounds__(256) void prep_kernel(const int* __restrict__ src,
                                                   const int* __restrict__ dst,
                                                   int* __restrict__ shard_cur,
                                                   int* __restrict__ deg,
                                                   unsigned long long* __restrict__ pairs, int E, int nBin,
                                                   const float* __restrict__ x,
                                                   const float* __restrict__ W1,
                                                   const float* __restrict__ W2,
                                                   const float* __restrict__ W3,
                                                   const float* __restrict__ Wp, const float* __restrict__ bp,
                                                   const float* __restrict__ Wc, const float* __restrict__ bc,
                                                   unsigned int* __restrict__ xb,
                                                   unsigned int* __restrict__ W1b,
                                                   unsigned int* __restrict__ W2b,
                                                   unsigned int* __restrict__ W3b,
                                                   unsigned int* __restrict__ Whb,
                                                   float* __restrict__ hbias,
                                                   int nx) {
    if ((int)blockIdx.x < nBin) {
        __shared__ int cnt[8];
        __shared__ int base[8];
        const int chunk = (E + nBin - 1) / nBin;
        const int lo = blockIdx.x * chunk;
        const int hi = min(lo + chunk, E);
        if (threadIdx.x < 8) cnt[threadIdx.x] = 0;
        __syncthreads();
        for (int e = lo + threadIdx.x; e < hi; e += 256) {
            int d = dst[e];
            atomicAdd(&cnt[(d >> 8) & 7], 1);
            atomicAdd(&deg[d], 1);          // fused degree count
        }
        __syncthreads();
        if (threadIdx.x < 8) {
            base[threadIdx.x] = atomicAdd(&shard_cur[threadIdx.x], cnt[threadIdx.x]);
            cnt[threadIdx.x] = 0;
        }
        __syncthreads();
        for (int e = lo + threadIdx.x; e < hi; e += 256) {
            int d = dst[e];
            int s = (d >> 8) & 7;
            int pos = s * REG_CAP + base[s] + atomicAdd(&cnt[s], 1);
            if (pos < (s + 1) * REG_CAP)
                pairs[pos] = ((unsigned long long)(unsigned int)d << 32) | (unsigned int)src[e];
        }
        return;
    }
    int i = (blockIdx.x - nBin) * 256 + threadIdx.x;
    const int T0 = nx;            // x pairs
    const int T1 = T0 + 4096;     // W1 128x64
    const int T2 = T1 + 8192;     // W2 128x128
    const int T3 = T2 + 4096;     // W3 64x128
    const int T4 = T3 + 2560;     // Whb 80x64
    const int T5 = T4 + 80;       // hbias
    if (i < T0) {
        float2 f = ((const float2*)x)[i];
        xb[i] = pack_bf2(f.x, f.y);
    } else if (i < T1) {
        float2 f = ((const float2*)W1)[i - T0];
        W1b[i - T0] = pack_bf2(f.x, f.y);
    } else if (i < T2) {
        float2 f = ((const float2*)W2)[i - T1];
        W2b[i - T1] = pack_bf2(f.x, f.y);
    } else if (i < T3) {
        float2 f = ((const float2*)W3)[i - T2];
        W3b[i - T2] = pack_bf2(f.x, f.y);
    } else if (i < T4) {
        int j = i - T3;
        int r = j >> 5, c = (j & 31) * 2;
        float v0 = 0.f, v1 = 0.f;
        if (r < 64)      { v0 = Wp[r * 64 + c]; v1 = Wp[r * 64 + c + 1]; }
        else if (r < 74) { v0 = Wc[(r - 64) * 64 + c]; v1 = Wc[(r - 64) * 64 + c + 1]; }
        Whb[j] = pack_bf2(v0, v1);
    } else if (i < T5) {
        int j = i - T4;
        float v = 0.f;
        if (j < 64)      v = bp[j];
        else if (j < 74) v = bc[j - 64];
        hbias[j] = v;
    }
}

__global__ __launch_bounds__(256) void scatter_binned_kernel(const unsigned long long* __restrict__ pairs,
                                                             const int* __restrict__ shard_cur,
                                                             int* __restrict__ cursor,
                                                             unsigned short* __restrict__ csr_src, int nSub) {
    const int s   = blockIdx.x & 7;
    const int sub = blockIdx.x >> 3;
    const int cnt = shard_cur[s];
    const int per = (cnt + nSub - 1) / nSub;
    const int lo = s * REG_CAP + sub * per;
    const int hi = min(lo + per, s * REG_CAP + cnt);
    for (int i = lo + threadIdx.x; i < hi; i += 256) {
        unsigned long long pr = pairs[i];
        int pos = atomicAdd(&cursor[(int)(pr >> 32)], 1);
        csr_src[pos] = (unsigned short)(pr & 0xffffu);
    }
}

// ---------------- scan ----------------

__global__ __launch_bounds__(256) void partial_sum_kernel(const int* __restrict__ deg,
                                                          int* __restrict__ partial, int n) {
    __shared__ int s[256];
    int t = threadIdx.x;
    int i = blockIdx.x * 256 + t;
    s[t] = (i < n) ? deg[i] : 0;
    __syncthreads();
    for (int off = 128; off > 0; off >>= 1) {
        if (t < off) s[t] += s[t + off];
        __syncthreads();
    }
    if (t == 0) partial[blockIdx.x] = s[0];
}

__global__ __launch_bounds__(256) void local_scan_kernel(const int* __restrict__ deg,
                                                         const int* __restrict__ partial,
                                                         int* __restrict__ offsets,
                                                         int* __restrict__ cursor, int nblocks, int n) {
    __shared__ int sp[256];
    __shared__ int s[256];
    int t = threadIdx.x;
    sp[t] = (t < nblocks) ? partial[t] : 0;
    __syncthreads();
    for (int off = 1; off < 256; off <<= 1) {
        int u = (t >= off) ? sp[t - off] : 0;
        __syncthreads();
        sp[t] += u;
        __syncthreads();
    }
    const int blockbase = (blockIdx.x == 0) ? 0 : sp[blockIdx.x - 1];
    if (blockIdx.x == 0 && t == 0) offsets[n] = sp[nblocks - 1];

    int i = blockIdx.x * 256 + t;
    int v = (i < n) ? deg[i] : 0;
    s[t] = v;
    __syncthreads();
    for (int off = 1; off < 256; off <<= 1) {
        int u = (t >= off) ? s[t - off] : 0;
        __syncthreads();
        s[t] += u;
        __syncthreads();
    }
    if (i < n) {
        int o = blockbase + s[t] - v;
        offsets[i] = o;
        cursor[i]  = o;
    }
}

// ---------------- Fused agg + MFMA GEMM per layer ----------------
// Block = 512 threads (8 waves), 32 nodes. Phase A: waves pull node tickets from an
// LDS counter (dynamic balancing), with a 2-deep software pipeline: offsets for node
// k+2 and csr chunk for node k+1 are prefetched while node k's gathers are in flight.
// Gathers use cascaded batch depths (8/4/2/1 passes) so a typical deg~16 node issues
// all its loads before the first wait. F=128 uses 16B/lane (dwordx4) gathers.
// Phase B: 8 waves MFMA the 32xF_OUT tile from LDS.
// MODE 0: bf16 out + relu.  MODE 3: relu, fp32 emb out, heads MFMA via LDS Ytile.

template <int F_IN, int F_OUT, int MODE>
__global__ __launch_bounds__(512) void fused_agg_gemm_kernel(
        const unsigned long long* __restrict__ xt,      // gather table, F_IN/4 u64 per row
        const int* __restrict__ offsets,
        const unsigned short* __restrict__ csr_src,
        const unsigned short* __restrict__ Wb,          // F_OUT x F_IN bf16
        const float* __restrict__ bias,
        unsigned short* __restrict__ Yb,                // MODE 0 out
        float* __restrict__ Yf,                         // MODE 3: emb out (fp32)
        float* __restrict__ nev, float* __restrict__ cls,
        const unsigned short* __restrict__ Whb, const float* __restrict__ hbias,
        int n) {
    constexpr int KC   = F_IN / 32;     // short8 chunks per row
    constexpr int XSTR = F_IN / 4;      // u64 per gather-table row
    constexpr int HSTR = F_IN + 8;      // LDS row stride (shorts), breaks pow2 banks
    __shared__ __align__(16) unsigned short Ht[32 * HSTR];
    __shared__ __align__(16) unsigned short Yt[(MODE == 3) ? 32 * 72 : 16];
    __shared__ int tick;

    const int lane = threadIdx.x & 63;
    const int m0   = blockIdx.x * 32;

    if (threadIdx.x == 0) tick = 0;
    __syncthreads();

    auto ticket = [&]() -> int {
        int t = 0;
        if (lane == 0) t = atomicAdd(&tick, 1);
        return __shfl(t, 0, 64);
    };

    // ---------- Phase A ----------
    if (F_IN == 64) {
        const int quad = lane >> 4;
        const int c    = lane & 15;

        // pipeline prologue
        int rA = ticket(); int sA = 0, eA = 0;
        if (rA < 32) { int nd = m0 + rA; if (nd < n) { sA = offsets[nd]; eA = offsets[nd + 1]; } }
        int rB = ticket(); int sB = 0, eB = 0;
        if (rB < 32) { int nd = m0 + rB; if (nd < n) { sB = offsets[nd]; eB = offsets[nd + 1]; } }
        int idxA = 0;
        if (eA > sA) { int ii = sA + lane; if (ii >= eA) ii = eA - 1; idxA = csr_src[ii]; }

        while (rA < 32) {
            int rC = ticket(); int sC = 0, eC = 0;
            if (rC < 32) { int nd = m0 + rC; if (nd < n) { sC = offsets[nd]; eC = offsets[nd + 1]; } }
            int idxB = 0;
            if (eB > sB) { int ii = sB + lane; if (ii >= eB) ii = eB - 1; idxB = csr_src[ii]; }

            const int node = m0 + rA;
            if (node < n) {
                float f0 = 0.f, f1 = 0.f, f2 = 0.f, f3 = 0.f;
                int e = sA;
                int idx = idxA;
                while (e < eA) {
                    int cnt = min(64, eA - e);
                    int j = 0;
                    for (; j + 32 <= cnt; j += 32) {
                        unsigned long long v[8];
#pragma unroll
                        for (int q = 0; q < 8; ++q) {
                            int nb = __shfl(idx, j + q * 4 + quad, 64);
                            v[q] = xt[(size_t)nb * XSTR + c];
                        }
#pragma unroll
                        for (int q = 0; q < 8; ++q) acc4(v[q], f0, f1, f2, f3);
                    }
                    if (j + 16 <= cnt) {
                        unsigned long long v[4];
#pragma unroll
                        for (int q = 0; q < 4; ++q) {
                            int nb = __shfl(idx, j + q * 4 + quad, 64);
                            v[q] = xt[(size_t)nb * XSTR + c];
                        }
#pragma unroll
                        for (int q = 0; q < 4; ++q) acc4(v[q], f0, f1, f2, f3);
                        j += 16;
                    }
                    if (j + 8 <= cnt) {
                        unsigned long long v[2];
#pragma unroll
                        for (int q = 0; q < 2; ++q) {
                            int nb = __shfl(idx, j + q * 4 + quad, 64);
                            v[q] = xt[(size_t)nb * XSTR + c];
                        }
#pragma unroll
                        for (int q = 0; q < 2; ++q) acc4(v[q], f0, f1, f2, f3);
                        j += 8;
                    }
                    if (j + 4 <= cnt) {
                        int nb = __shfl(idx, j + quad, 64);
                        acc4(xt[(size_t)nb * XSTR + c], f0, f1, f2, f3);
                        j += 4;
                    }
                    int rem = cnt - j;
                    if (rem > 0) {                         // wave-uniform
                        int sl = j + quad;
                        sl = (sl < cnt) ? sl : (cnt - 1);  // keep source lane active
                        int nb = __shfl(idx, sl, 64);
                        if (quad < rem) acc4(xt[(size_t)nb * XSTR + c], f0, f1, f2, f3);
                    }
                    e += cnt;
                    if (e < eA) { int ii = e + lane; if (ii >= eA) ii = eA - 1; idx = csr_src[ii]; }
                }
                f0 += __shfl(f0, lane ^ 16, 64); f1 += __shfl(f1, lane ^ 16, 64);
                f2 += __shfl(f2, lane ^ 16, 64); f3 += __shfl(f3, lane ^ 16, 64);
                f0 += __shfl(f0, lane ^ 32, 64); f1 += __shfl(f1, lane ^ 32, 64);
                f2 += __shfl(f2, lane ^ 32, 64); f3 += __shfl(f3, lane ^ 32, 64);
                if (quad == 0) {
                    float inv = 1.0f / fmaxf((float)(eA - sA), 1.0f);
                    unsigned long long sv = xt[(size_t)node * XSTR + c];
                    unsigned ua = (unsigned)sv, ub = (unsigned)(sv >> 32);
                    unsigned o0 = pack_bf2(f0 * inv + bf_lo(ua), f1 * inv + bf_hi(ua));
                    unsigned o1 = pack_bf2(f2 * inv + bf_lo(ub), f3 * inv + bf_hi(ub));
                    *(unsigned long long*)&Ht[rA * HSTR + c * 4] =
                        ((unsigned long long)o1 << 32) | o0;
                }
            } else if (quad == 0) {
                *(unsigned long long*)&Ht[rA * HSTR + c * 4] = 0ull;
            }
            rA = rB; sA = sB; eA = eB; idxA = idxB;
            rB = rC; sB = sC; eB = eC;
        }
    } else {
        const int g = lane >> 4;       // 4 edge groups of 16 lanes
        const int c = lane & 15;       // 16B chunk index within row

        int rA = ticket(); int sA = 0, eA = 0;
        if (rA < 32) { int nd = m0 + rA; if (nd < n) { sA = offsets[nd]; eA = offsets[nd + 1]; } }
        int rB = ticket(); int sB = 0, eB = 0;
        if (rB < 32) { int nd = m0 + rB; if (nd < n) { sB = offsets[nd]; eB = offsets[nd + 1]; } }
        int idxA = 0;
        if (eA > sA) { int ii = sA + lane; if (ii >= eA) ii = eA - 1; idxA = csr_src[ii]; }

        while (rA < 32) {
            int rC = ticket(); int sC = 0, eC = 0;
            if (rC < 32) { int nd = m0 + rC; if (nd < n) { sC = offsets[nd]; eC = offsets[nd + 1]; } }
            int idxB = 0;
            if (eB > sB) { int ii = sB + lane; if (ii >= eB) ii = eB - 1; idxB = csr_src[ii]; }

            const int node = m0 + rA;
            if (node < n) {
                float f0 = 0.f, f1 = 0.f, f2 = 0.f, f3 = 0.f;
                float f4 = 0.f, f5 = 0.f, f6 = 0.f, f7 = 0.f;
                int e = sA;
                int idx = idxA;
                while (e < eA) {
                    int cnt = min(64, eA - e);
                    int j = 0;
                    for (; j + 32 <= cnt; j += 32) {
                        ulonglong2 v[8];
#pragma unroll
                        for (int q = 0; q < 8; ++q) {
                            int nb = __shfl(idx, j + q * 4 + g, 64);
                            v[q] = *(const ulonglong2*)&xt[(size_t)nb * XSTR + c * 2];
                        }
#pragma unroll
                        for (int q = 0; q < 8; ++q) acc8(v[q], f0, f1, f2, f3, f4, f5, f6, f7);
                    }
                    if (j + 16 <= cnt) {
                        ulonglong2 v[4];
#pragma unroll
                        for (int q = 0; q < 4; ++q) {
                            int nb = __shfl(idx, j + q * 4 + g, 64);
                            v[q] = *(const ulonglong2*)&xt[(size_t)nb * XSTR + c * 2];
                        }
#pragma unroll
                        for (int q = 0; q < 4; ++q) acc8(v[q], f0, f1, f2, f3, f4, f5, f6, f7);
                        j += 16;
                    }
                    if (j + 8 <= cnt) {
                        ulonglong2 v[2];
#pragma unroll
                        for (int q = 0; q < 2; ++q) {
                            int nb = __shfl(idx, j + q * 4 + g, 64);
                            v[q] = *(const ulonglong2*)&xt[(size_t)nb * XSTR + c * 2];
                        }
#pragma unroll
                        for (int q = 0; q < 2; ++q) acc8(v[q], f0, f1, f2, f3, f4, f5, f6, f7);
                        j += 8;
                    }
                    if (j + 4 <= cnt) {
                        int nb = __shfl(idx, j + g, 64);
                        acc8(*(const ulonglong2*)&xt[(size_t)nb * XSTR + c * 2],
                             f0, f1, f2, f3, f4, f5, f6, f7);
                        j += 4;
                    }
                    int rem = cnt - j;                     // 0..3
                    if (rem > 0) {                         // wave-uniform
                        int sl = j + g;
                        sl = (sl < cnt) ? sl : (cnt - 1);  // keep source lane active
                        int nb = __shfl(idx, sl, 64);
                        if (g < rem)
                            acc8(*(const ulonglong2*)&xt[(size_t)nb * XSTR + c * 2],
                                 f0, f1, f2, f3, f4, f5, f6, f7);
                    }
                    e += cnt;
                    if (e < eA) { int ii = e + lane; if (ii >= eA) ii = eA - 1; idx = csr_src[ii]; }
                }
                // reduce over the 4 edge groups
                f0 += __shfl(f0, lane ^ 16, 64); f1 += __shfl(f1, lane ^ 16, 64);
                f2 += __shfl(f2, lane ^ 16, 64); f3 += __shfl(f3, lane ^ 16, 64);
                f4 += __shfl(f4, lane ^ 16, 64); f5 += __shfl(f5, lane ^ 16, 64);
                f6 += __shfl(f6, lane ^ 16, 64); f7 += __shfl(f7, lane ^ 16, 64);
                f0 += __shfl(f0, lane ^ 32, 64); f1 += __shfl(f1, lane ^ 32, 64);
                f2 += __shfl(f2, lane ^ 32, 64); f3 += __shfl(f3, lane ^ 32, 64);
                f4 += __shfl(f4, lane ^ 32, 64); f5 += __shfl(f5, lane ^ 32, 64);
                f6 += __shfl(f6, lane ^ 32, 64); f7 += __shfl(f7, lane ^ 32, 64);
                if (g == 0) {
                    float inv = 1.0f / fmaxf((float)(eA - sA), 1.0f);
                    ulonglong2 sv = *(const ulonglong2*)&xt[(size_t)node * XSTR + c * 2];
                    unsigned ua0 = (unsigned)sv.x, ub0 = (unsigned)(sv.x >> 32);
                    unsigned ua1 = (unsigned)sv.y, ub1 = (unsigned)(sv.y >> 32);
                    unsigned o0 = pack_bf2(f0 * inv + bf_lo(ua0), f1 * inv + bf_hi(ua0));
                    unsigned o1 = pack_bf2(f2 * inv + bf_lo(ub0), f3 * inv + bf_hi(ub0));
                    unsigned o2 = pack_bf2(f4 * inv + bf_lo(ua1), f5 * inv + bf_hi(ua1));
                    unsigned o3 = pack_bf2(f6 * inv + bf_lo(ub1), f7 * inv + bf_hi(ub1));
                    ulonglong2 ov;
                    ov.x = ((unsigned long long)o1 << 32) | o0;
                    ov.y = ((unsigned long long)o3 << 32) | o2;
                    *(ulonglong2*)&Ht[rA * HSTR + c * 8] = ov;
                }
            } else if (g == 0) {
                ulonglong2 z; z.x = 0; z.y = 0;
                *(ulonglong2*)&Ht[rA * HSTR + c * 8] = z;
            }
            rA = rB; sA = sB; eA = eB; idxA = idxB;
            rB = rC; sB = sC; eB = eC;
        }
    }
    __syncthreads();

    // ---------- Phase B: MFMA on the 32-row tile ----------
    const int wv   = threadIdx.x >> 6;
    const int quad = lane >> 4;
    const int r16  = lane & 15;

    if (MODE == 0) {
        // 32 x F_OUT(=128): 2 row-groups x 8 col-groups = 16 tiles, 2 per wave
        const int rowg = wv & 1;
        const int cg0  = (wv >> 1) * 2;
        short8 a[KC];
#pragma unroll
        for (int c = 0; c < KC; ++c)
            a[c] = *(const short8*)&Ht[(16 * rowg + r16) * HSTR + 32 * c + quad * 8];

        floatx4 acc[2];
#pragma unroll
        for (int j = 0; j < 2; ++j)
#pragma unroll
            for (int r = 0; r < 4; ++r) acc[j][r] = 0.f;

#pragma unroll
        for (int j = 0; j < 2; ++j)
#pragma unroll
            for (int c = 0; c < KC; ++c) {
                short8 b = *(const short8*)&Wb[(size_t)(16 * (cg0 + j) + r16) * F_IN + 32 * c + quad * 8];
                acc[j] = __builtin_amdgcn_mfma_f32_16x16x32_bf16(a[c], b, acc[j], 0, 0, 0);
            }

#pragma unroll
        for (int r = 0; r < 4; ++r) {
            const int mm = m0 + 16 * rowg + quad * 4 + r;
            if (mm >= n) continue;
#pragma unroll
            for (int j = 0; j < 2; ++j) {
                const int o = 16 * (cg0 + j) + r16;
                Yb[(size_t)mm * F_OUT + o] = f2bf_rne(fmaxf(acc[j][r] + bias[o], 0.f));
            }
        }
    } else {
        // layer3: 32 x 64 = 2 x 4 tiles, 1 per wave; then heads from LDS Ytile
        const int rowg = wv & 1;
        const int cg   = wv >> 1;      // 0..3
        short8 a[KC];
#pragma unroll
        for (int c = 0; c < KC; ++c)
            a[c] = *(const short8*)&Ht[(16 * rowg + r16) * HSTR + 32 * c + quad * 8];

        floatx4 acc;
#pragma unroll
        for (int r = 0; r < 4; ++r) acc[r] = 0.f;

#pragma unroll
        for (int c = 0; c < KC; ++c) {
            short8 b = *(const short8*)&Wb[(size_t)(16 * cg + r16) * F_IN + 32 * c + quad * 8];
            acc = __builtin_amdgcn_mfma_f32_16x16x32_bf16(a[c], b, acc, 0, 0, 0);
        }

#pragma unroll
        for (int r = 0; r < 4; ++r) {
            const int lr = 16 * rowg + quad * 4 + r;
            const int mm = m0 + lr;
            const int o  = 16 * cg + r16;
            if (mm < n) {
                float v = fmaxf(acc[r] + bias[o], 0.f);
                Yf[(size_t)mm * 64 + o] = v;
                Yt[lr * 72 + o] = f2bf_rne(v);
            } else {
                Yt[lr * 72 + o] = 0;
            }
        }
        __syncthreads();

        // heads: 32 x 80 = 2 x 5 tiles = 10, waves 0..7 take t=wv, waves 0..1 also t=8+wv
        for (int t = wv; t < 10; t += 8) {
            const int rg  = t & 1;
            const int cg2 = t >> 1;    // 0..4
            short8 a2[2];
#pragma unroll
            for (int c = 0; c < 2; ++c)
                a2[c] = *(const short8*)&Yt[(16 * rg + r16) * 72 + 32 * c + quad * 8];

            floatx4 acc2;
#pragma unroll
            for (int r = 0; r < 4; ++r) acc2[r] = 0.f;

#pragma unroll
            for (int c = 0; c < 2; ++c) {
                short8 b = *(const short8*)&Whb[(size_t)(16 * cg2 + r16) * 64 + 32 * c + quad * 8];
                acc2 = __builtin_amdgcn_mfma_f32_16x16x32_bf16(a2[c], b, acc2, 0, 0, 0);
            }

#pragma unroll
            for (int r = 0; r < 4; ++r) {
                const int mm = m0 + 16 * rg + quad * 4 + r;
                if (mm >= n) continue;
                const int o = 16 * cg2 + r16;
                float v = acc2[r] + hbias[o];
                if (o < 64)      nev[(size_t)mm * 64 + o] = v;
                else if (o < 74) cls[(size_t)mm * 10 + (o - 64)] = v;
            }
        }
    }
}

// ---------------- launch ----------------

extern "C" void kernel_launch(void* const* d_in, const int* in_sizes, int n_in,
                              void* d_out, int out_size, void* d_ws, size_t ws_size,
                              hipStream_t stream) {
    const float* x  = (const float*)d_in[0];
    const int*   ei = (const int*)d_in[1];
    const float* W1 = (const float*)d_in[2];
    const float* b1 = (const float*)d_in[3];
    const float* W2 = (const float*)d_in[4];
    const float* b2 = (const float*)d_in[5];
    const float* W3 = (const float*)d_in[6];
    const float* b3 = (const float*)d_in[7];
    const float* Wp = (const float*)d_in[8];
    const float* bp = (const float*)d_in[9];
    const float* Wc = (const float*)d_in[10];
    const float* bc = (const float*)d_in[11];

    const int n = in_sizes[0] / 64;   // 50000
    const int E = in_sizes[1] / 2;    // 800000
    const int* src = ei;
    const int* dst = ei + E;

    const int nScanBlocks = (n + 255) / 256;   // 196

    // workspace layout (deg and shard_cur adjacent: one memset zeroes both)
    int* deg       = (int*)d_ws;              // n
    int* shard_cur = deg + n;                 // 8
    int* offsets   = shard_cur + 8;           // n+1
    int* cursor    = offsets + (n + 1);       // n
    int* partial   = cursor + n;              // 256
    unsigned short* csr_src = (unsigned short*)(partial + 256);   // E u16
    uintptr_t p = (uintptr_t)(csr_src + E);
    p = (p + 255) & ~(uintptr_t)255;
    unsigned long long* pairs = (unsigned long long*)p;        // 8*REG_CAP
    unsigned int* Hb  = (unsigned int*)(pairs + 8 * REG_CAP);  // n*64 (n x 128 bf16)
    unsigned int* Yb  = Hb + (size_t)n * 64;       // n*64 (n x 128 bf16)
    unsigned int* xb  = Yb + (size_t)n * 64;       // n*32 (n x 64 bf16)
    unsigned int* W1b = xb + (size_t)n * 32;       // 4096 uints
    unsigned int* W2b = W1b + 4096;                // 8192
    unsigned int* W3b = W2b + 8192;                // 4096
    unsigned int* Whb = W3b + 4096;                // 2560
    float* hbias = (float*)(Whb + 2560);           // 80

    float* out_emb = (float*)d_out;
    float* out_nev = out_emb + (size_t)n * 64;
    float* out_cls = out_nev + (size_t)n * 64;

    hipMemsetAsync(deg, 0, (size_t)(n + 8) * sizeof(int), stream);

    const int nBin = 256;
    const int convTotal = n * 32 + 4096 + 8192 + 4096 + 2560 + 80;
    const int convBlocks = (convTotal + 255) / 256;
    prep_kernel<<<nBin + convBlocks, 256, 0, stream>>>(
        src, dst, shard_cur, deg, pairs, E, nBin,
        x, W1, W2, W3, Wp, bp, Wc, bc, xb, W1b, W2b, W3b, Whb, hbias, n * 32);

    partial_sum_kernel<<<nScanBlocks, 256, 0, stream>>>(deg, partial, n);
    local_scan_kernel<<<nScanBlocks, 256, 0, stream>>>(deg, partial, offsets, cursor, nScanBlocks, n);

    const int nSub = 64;   // 8 shards x 64 = 512 blocks
    scatter_binned_kernel<<<8 * nSub, 256, 0, stream>>>(pairs, shard_cur, cursor, csr_src, nSub);

    const int gF = (n + 31) / 32;    // 1563 blocks, 512 threads

    // layer 1: agg(x, F=64) + GEMM 64->128 -> Hb (bf16)
    fused_agg_gemm_kernel<64, 128, 0><<<gF, 512, 0, stream>>>(
        (const unsigned long long*)xb, offsets, csr_src,
        (const unsigned short*)W1b, b1, (unsigned short*)Hb,
        nullptr, nullptr, nullptr, nullptr, nullptr, n);

    // layer 2: agg(Hb, F=128) + GEMM 128->128 -> Yb (bf16)
    fused_agg_gemm_kernel<128, 128, 0><<<gF, 512, 0, stream>>>(
        (const unsigned long long*)Hb, offsets, csr_src,
        (const unsigned short*)W2b, b2, (unsigned short*)Yb,
        nullptr, nullptr, nullptr, nullptr, nullptr, n);

    // layer 3: agg(Yb, F=128) + GEMM 128->64 + heads -> out_emb / nev / cls
    fused_agg_gemm_kernel<128, 64, 3><<<gF, 512, 0, stream>>>(
        (const unsigned long long*)Yb, offsets, csr_src,
        (const unsigned short*)W3b, b3, nullptr,
        out_emb, out_nev, out_cls, (const unsigned short*)Whb, hbias, n);
}

// Round 3
// 297.468 us; speedup vs baseline: 1.0545x; 1.0545x over previous
//
#include <hip/hip_runtime.h>
#include <hip/hip_bf16.h>

typedef __attribute__((ext_vector_type(8))) short short8;
typedef __attribute__((ext_vector_type(4))) float floatx4;

__device__ __forceinline__ float bf_lo(unsigned int u) { return __uint_as_float(u << 16); }
__device__ __forceinline__ float bf_hi(unsigned int u) { return __uint_as_float(u & 0xffff0000u); }

__device__ __forceinline__ unsigned short f2bf_rne(float f) {
    unsigned u = __float_as_uint(f);
    unsigned rb = (u >> 16) & 1u;
    u += 0x7fffu + rb;
    return (unsigned short)(u >> 16);
}
__device__ __forceinline__ unsigned int pack_bf2(float x, float y) {
    return (unsigned int)f2bf_rne(x) | ((unsigned int)f2bf_rne(y) << 16);
}

__device__ __forceinline__ void acc4(unsigned long long v, float& f0, float& f1, float& f2, float& f3) {
    unsigned ua = (unsigned)v, ub = (unsigned)(v >> 32);
    f0 += bf_lo(ua); f1 += bf_hi(ua); f2 += bf_lo(ub); f3 += bf_hi(ub);
}

// ---------------- prep: deg-count (blocks [0,nCnt)) + convert/pack (rest) ----------------
// deg pre-zeroed by memset. No pairs/binning: scatter reads the edge list directly.

__global__ __launch_bounds__(256) void prep_kernel(const int* __restrict__ dst,
                                                   int* __restrict__ deg, int E, int nCnt,
                                                   const float* __restrict__ x,
                                                   const float* __restrict__ W1,
                                                   const float* __restrict__ W2,
                                                   const float* __restrict__ W3,
                                                   const float* __restrict__ Wp, const float* __restrict__ bp,
                                                   const float* __restrict__ Wc, const float* __restrict__ bc,
                                                   unsigned int* __restrict__ xb,
                                                   unsigned int* __restrict__ W1b,
                                                   unsigned int* __restrict__ W2b,
                                                   unsigned int* __restrict__ W3b,
                                                   unsigned int* __restrict__ Whb,
                                                   float* __restrict__ hbias,
                                                   int nx) {
    if ((int)blockIdx.x < nCnt) {
        const int chunk = (E + nCnt - 1) / nCnt;
        const int lo = blockIdx.x * chunk;
        const int hi = min(lo + chunk, E);
        for (int e = lo + threadIdx.x; e < hi; e += 256)
            atomicAdd(&deg[dst[e]], 1);
        return;
    }
    int i = (blockIdx.x - nCnt) * 256 + threadIdx.x;
    const int T0 = nx;            // x pairs
    const int T1 = T0 + 4096;     // W1 128x64
    const int T2 = T1 + 8192;     // W2 128x128
    const int T3 = T2 + 4096;     // W3 64x128
    const int T4 = T3 + 2560;     // Whb 80x64
    const int T5 = T4 + 80;       // hbias
    if (i < T0) {
        float2 f = ((const float2*)x)[i];
        xb[i] = pack_bf2(f.x, f.y);
    } else if (i < T1) {
        float2 f = ((const float2*)W1)[i - T0];
        W1b[i - T0] = pack_bf2(f.x, f.y);
    } else if (i < T2) {
        float2 f = ((const float2*)W2)[i - T1];
        W2b[i - T1] = pack_bf2(f.x, f.y);
    } else if (i < T3) {
        float2 f = ((const float2*)W3)[i - T2];
        W3b[i - T2] = pack_bf2(f.x, f.y);
    } else if (i < T4) {
        int j = i - T3;
        int r = j >> 5, c = (j & 31) * 2;
        float v0 = 0.f, v1 = 0.f;
        if (r < 64)      { v0 = Wp[r * 64 + c]; v1 = Wp[r * 64 + c + 1]; }
        else if (r < 74) { v0 = Wc[(r - 64) * 64 + c]; v1 = Wc[(r - 64) * 64 + c + 1]; }
        Whb[j] = pack_bf2(v0, v1);
    } else if (i < T5) {
        int j = i - T4;
        float v = 0.f;
        if (j < 64)      v = bp[j];
        else if (j < 74) v = bc[j - 64];
        hbias[j] = v;
    }
}

// direct scatter: edge list -> csr_src via cursor atomics (order within a node is racy,
// same as before — rounding-only effect, absorbed by tolerance)
__global__ __launch_bounds__(256) void scatter_kernel(const int* __restrict__ src,
                                                      const int* __restrict__ dst,
                                                      int* __restrict__ cursor,
                                                      unsigned short* __restrict__ csr_src, int E) {
    const int stride = gridDim.x * 256;
    for (int i = blockIdx.x * 256 + threadIdx.x; i < E; i += stride) {
        int pos = atomicAdd(&cursor[dst[i]], 1);
        csr_src[pos] = (unsigned short)src[i];
    }
}

// ---------------- scan ----------------

__global__ __launch_bounds__(256) void partial_sum_kernel(const int* __restrict__ deg,
                                                          int* __restrict__ partial, int n) {
    __shared__ int s[256];
    int t = threadIdx.x;
    int i = blockIdx.x * 256 + t;
    s[t] = (i < n) ? deg[i] : 0;
    __syncthreads();
    for (int off = 128; off > 0; off >>= 1) {
        if (t < off) s[t] += s[t + off];
        __syncthreads();
    }
    if (t == 0) partial[blockIdx.x] = s[0];
}

__global__ __launch_bounds__(256) void local_scan_kernel(const int* __restrict__ deg,
                                                         const int* __restrict__ partial,
                                                         int* __restrict__ offsets,
                                                         int* __restrict__ cursor, int nblocks, int n) {
    __shared__ int sp[256];
    __shared__ int s[256];
    int t = threadIdx.x;
    sp[t] = (t < nblocks) ? partial[t] : 0;
    __syncthreads();
    for (int off = 1; off < 256; off <<= 1) {
        int u = (t >= off) ? sp[t - off] : 0;
        __syncthreads();
        sp[t] += u;
        __syncthreads();
    }
    const int blockbase = (blockIdx.x == 0) ? 0 : sp[blockIdx.x - 1];
    if (blockIdx.x == 0 && t == 0) offsets[n] = sp[nblocks - 1];

    int i = blockIdx.x * 256 + t;
    int v = (i < n) ? deg[i] : 0;
    s[t] = v;
    __syncthreads();
    for (int off = 1; off < 256; off <<= 1) {
        int u = (t >= off) ? s[t - off] : 0;
        __syncthreads();
        s[t] += u;
        __syncthreads();
    }
    if (i < n) {
        int o = blockbase + s[t] - v;
        offsets[i] = o;
        cursor[i]  = o;
    }
}

// ---------------- Fused agg + MFMA GEMM per layer ----------------
// Block = 512 threads (8 waves), 32 nodes. Phase A: each wave aggregates 4 nodes
// (round-1 proven structure) into an LDS tile. Cascaded batch depths (8/4/2/1-deep
// load batches) keep more gathers in flight for mid-degree nodes; batching preserves
// the exact per-lane accumulation order (bit-identical numerics).
// Phase B: 8 waves MFMA the 32xF_OUT tile from LDS.
// MODE 0: bf16 out + relu.  MODE 3: relu, fp32 emb out, heads MFMA via LDS Ytile.

template <int F_IN, int F_OUT, int MODE>
__global__ __launch_bounds__(512) void fused_agg_gemm_kernel(
        const unsigned long long* __restrict__ xt,      // gather table, F_IN/4 u64 per row
        const int* __restrict__ offsets,
        const unsigned short* __restrict__ csr_src,
        const unsigned short* __restrict__ Wb,          // F_OUT x F_IN bf16
        const float* __restrict__ bias,
        unsigned short* __restrict__ Yb,                // MODE 0 out
        float* __restrict__ Yf,                         // MODE 3: emb out (fp32)
        float* __restrict__ nev, float* __restrict__ cls,
        const unsigned short* __restrict__ Whb, const float* __restrict__ hbias,
        int n) {
    constexpr int KC   = F_IN / 32;     // short8 chunks per row
    constexpr int XSTR = F_IN / 4;      // u64 per gather-table row
    constexpr int HSTR = F_IN + 8;      // LDS row stride (shorts), breaks pow2 banks
    __shared__ __align__(16) unsigned short Ht[32 * HSTR];
    __shared__ __align__(16) unsigned short Yt[(MODE == 3) ? 32 * 72 : 16];

    const int lane = threadIdx.x & 63;
    const int wv   = threadIdx.x >> 6;      // 0..7
    const int m0   = blockIdx.x * 32;

    // ---------- Phase A: aggregation, 4 nodes per wave ----------
    if (F_IN == 64) {
        const int quad = lane >> 4;
        const int c    = lane & 15;
#pragma unroll 1
        for (int i = 0; i < 4; ++i) {
            const int row  = wv * 4 + i;
            const int node = m0 + row;
            if (node < n) {
                const int start = offsets[node];
                const int end   = offsets[node + 1];
                float s0 = 0.f, s1 = 0.f, s2 = 0.f, s3 = 0.f;
                int e = start;
                while (e < end) {
                    int cnt = min(64, end - e);
                    int ii = e + lane; if (ii >= end) ii = end - 1;
                    int idx = csr_src[ii];
                    int j = 0;
                    for (; j + 32 <= cnt; j += 32) {
                        unsigned long long v[8];
#pragma unroll
                        for (int q = 0; q < 8; ++q) {
                            int nb = __shfl(idx, j + q * 4 + quad, 64);
                            v[q] = xt[(size_t)nb * XSTR + c];
                        }
#pragma unroll
                        for (int q = 0; q < 8; ++q) acc4(v[q], s0, s1, s2, s3);
                    }
                    if (j + 16 <= cnt) {
                        unsigned long long v[4];
#pragma unroll
                        for (int q = 0; q < 4; ++q) {
                            int nb = __shfl(idx, j + q * 4 + quad, 64);
                            v[q] = xt[(size_t)nb * XSTR + c];
                        }
#pragma unroll
                        for (int q = 0; q < 4; ++q) acc4(v[q], s0, s1, s2, s3);
                        j += 16;
                    }
                    if (j + 8 <= cnt) {
                        unsigned long long v[2];
#pragma unroll
                        for (int q = 0; q < 2; ++q) {
                            int nb = __shfl(idx, j + q * 4 + quad, 64);
                            v[q] = xt[(size_t)nb * XSTR + c];
                        }
#pragma unroll
                        for (int q = 0; q < 2; ++q) acc4(v[q], s0, s1, s2, s3);
                        j += 8;
                    }
                    if (j + 4 <= cnt) {
                        int nb = __shfl(idx, j + quad, 64);
                        acc4(xt[(size_t)nb * XSTR + c], s0, s1, s2, s3);
                        j += 4;
                    }
                    int rem = cnt - j;
                    if (rem > 0) {                         // wave-uniform
                        int sl = j + quad;
                        sl = (sl < cnt) ? sl : (cnt - 1);  // keep source lane active
                        int nb = __shfl(idx, sl, 64);      // all lanes execute
                        if (quad < rem) acc4(xt[(size_t)nb * XSTR + c], s0, s1, s2, s3);
                    }
                    e += cnt;
                }
                s0 += __shfl(s0, lane ^ 16, 64); s1 += __shfl(s1, lane ^ 16, 64);
                s2 += __shfl(s2, lane ^ 16, 64); s3 += __shfl(s3, lane ^ 16, 64);
                s0 += __shfl(s0, lane ^ 32, 64); s1 += __shfl(s1, lane ^ 32, 64);
                s2 += __shfl(s2, lane ^ 32, 64); s3 += __shfl(s3, lane ^ 32, 64);
                if (quad == 0) {
                    float inv = 1.0f / fmaxf((float)(end - start), 1.0f);
                    unsigned long long sv = xt[(size_t)node * XSTR + c];
                    unsigned ua = (unsigned)sv, ub = (unsigned)(sv >> 32);
                    unsigned o0 = pack_bf2(s0 * inv + bf_lo(ua), s1 * inv + bf_hi(ua));
                    unsigned o1 = pack_bf2(s2 * inv + bf_lo(ub), s3 * inv + bf_hi(ub));
                    *(unsigned long long*)&Ht[row * HSTR + c * 4] =
                        ((unsigned long long)o1 << 32) | o0;
                }
            } else if (quad == 0) {
                *(unsigned long long*)&Ht[row * HSTR + c * 4] = 0ull;
            }
        }
    } else {
        const int half = lane >> 5;
        const int c    = lane & 31;
#pragma unroll 1
        for (int i = 0; i < 4; ++i) {
            const int row  = wv * 4 + i;
            const int node = m0 + row;
            if (node < n) {
                const int start = offsets[node];
                const int end   = offsets[node + 1];
                float s0 = 0.f, s1 = 0.f, s2 = 0.f, s3 = 0.f;
                int e = start;
                while (e < end) {
                    int cnt = min(64, end - e);
                    int ii = e + lane; if (ii >= end) ii = end - 1;
                    int idx = csr_src[ii];
                    int j = 0;
                    for (; j + 16 <= cnt; j += 16) {
                        unsigned long long v[8];
#pragma unroll
                        for (int q = 0; q < 8; ++q) {
                            int nb = __shfl(idx, j + q * 2 + half, 64);
                            v[q] = xt[(size_t)nb * XSTR + c];
                        }
#pragma unroll
                        for (int q = 0; q < 8; ++q) acc4(v[q], s0, s1, s2, s3);
                    }
                    if (j + 8 <= cnt) {
                        unsigned long long v[4];
#pragma unroll
                        for (int q = 0; q < 4; ++q) {
                            int nb = __shfl(idx, j + q * 2 + half, 64);
                            v[q] = xt[(size_t)nb * XSTR + c];
                        }
#pragma unroll
                        for (int q = 0; q < 4; ++q) acc4(v[q], s0, s1, s2, s3);
                        j += 8;
                    }
                    if (j + 4 <= cnt) {
                        unsigned long long v[2];
#pragma unroll
                        for (int q = 0; q < 2; ++q) {
                            int nb = __shfl(idx, j + q * 2 + half, 64);
                            v[q] = xt[(size_t)nb * XSTR + c];
                        }
#pragma unroll
                        for (int q = 0; q < 2; ++q) acc4(v[q], s0, s1, s2, s3);
                        j += 4;
                    }
                    if (j + 2 <= cnt) {
                        int nb = __shfl(idx, j + half, 64);
                        acc4(xt[(size_t)nb * XSTR + c], s0, s1, s2, s3);
                        j += 2;
                    }
                    if (j < cnt) {                         // wave-uniform, rem == 1
                        int nb = __shfl(idx, j, 64);       // all lanes execute
                        if (half == 0) acc4(xt[(size_t)nb * XSTR + c], s0, s1, s2, s3);
                    }
                    e += cnt;
                }
                s0 += __shfl(s0, lane ^ 32, 64); s1 += __shfl(s1, lane ^ 32, 64);
                s2 += __shfl(s2, lane ^ 32, 64); s3 += __shfl(s3, lane ^ 32, 64);
                if (half == 0) {
                    float inv = 1.0f / fmaxf((float)(end - start), 1.0f);
                    unsigned long long sv = xt[(size_t)node * XSTR + c];
                    unsigned ua = (unsigned)sv, ub = (unsigned)(sv >> 32);
                    unsigned o0 = pack_bf2(s0 * inv + bf_lo(ua), s1 * inv + bf_hi(ua));
                    unsigned o1 = pack_bf2(s2 * inv + bf_lo(ub), s3 * inv + bf_hi(ub));
                    *(unsigned long long*)&Ht[row * HSTR + c * 4] =
                        ((unsigned long long)o1 << 32) | o0;
                }
            } else if (half == 0) {
                *(unsigned long long*)&Ht[row * HSTR + c * 4] = 0ull;
            }
        }
    }
    __syncthreads();

    // ---------- Phase B: MFMA on the 32-row tile ----------
    const int quad = lane >> 4;
    const int r16  = lane & 15;

    if (MODE == 0) {
        // 32 x F_OUT(=128): 2 row-groups x 8 col-groups = 16 tiles, 2 per wave
        const int rowg = wv & 1;
        const int cg0  = (wv >> 1) * 2;
        short8 a[KC];
#pragma unroll
        for (int c = 0; c < KC; ++c)
            a[c] = *(const short8*)&Ht[(16 * rowg + r16) * HSTR + 32 * c + quad * 8];

        floatx4 acc[2];
#pragma unroll
        for (int j = 0; j < 2; ++j)
#pragma unroll
            for (int r = 0; r < 4; ++r) acc[j][r] = 0.f;

#pragma unroll
        for (int j = 0; j < 2; ++j)
#pragma unroll
            for (int c = 0; c < KC; ++c) {
                short8 b = *(const short8*)&Wb[(size_t)(16 * (cg0 + j) + r16) * F_IN + 32 * c + quad * 8];
                acc[j] = __builtin_amdgcn_mfma_f32_16x16x32_bf16(a[c], b, acc[j], 0, 0, 0);
            }

#pragma unroll
        for (int r = 0; r < 4; ++r) {
            const int mm = m0 + 16 * rowg + quad * 4 + r;
            if (mm >= n) continue;
#pragma unroll
            for (int j = 0; j < 2; ++j) {
                const int o = 16 * (cg0 + j) + r16;
                Yb[(size_t)mm * F_OUT + o] = f2bf_rne(fmaxf(acc[j][r] + bias[o], 0.f));
            }
        }
    } else {
        // layer3: 32 x 64 = 2 x 4 tiles, 1 per wave; then heads from LDS Ytile
        const int rowg = wv & 1;
        const int cg   = wv >> 1;      // 0..3
        short8 a[KC];
#pragma unroll
        for (int c = 0; c < KC; ++c)
            a[c] = *(const short8*)&Ht[(16 * rowg + r16) * HSTR + 32 * c + quad * 8];

        floatx4 acc;
#pragma unroll
        for (int r = 0; r < 4; ++r) acc[r] = 0.f;

#pragma unroll
        for (int c = 0; c < KC; ++c) {
            short8 b = *(const short8*)&Wb[(size_t)(16 * cg + r16) * F_IN + 32 * c + quad * 8];
            acc = __builtin_amdgcn_mfma_f32_16x16x32_bf16(a[c], b, acc, 0, 0, 0);
        }

#pragma unroll
        for (int r = 0; r < 4; ++r) {
            const int lr = 16 * rowg + quad * 4 + r;
            const int mm = m0 + lr;
            const int o  = 16 * cg + r16;
            if (mm < n) {
                float v = fmaxf(acc[r] + bias[o], 0.f);
                Yf[(size_t)mm * 64 + o] = v;
                Yt[lr * 72 + o] = f2bf_rne(v);
            } else {
                Yt[lr * 72 + o] = 0;
            }
        }
        __syncthreads();

        // heads: 32 x 80 = 2 x 5 tiles = 10, waves 0..7 take t=wv, waves 0..1 also t=8+wv
        for (int t = wv; t < 10; t += 8) {
            const int rg  = t & 1;
            const int cg2 = t >> 1;    // 0..4
            short8 a2[2];
#pragma unroll
            for (int c = 0; c < 2; ++c)
                a2[c] = *(const short8*)&Yt[(16 * rg + r16) * 72 + 32 * c + quad * 8];

            floatx4 acc2;
#pragma unroll
            for (int r = 0; r < 4; ++r) acc2[r] = 0.f;

#pragma unroll
            for (int c = 0; c < 2; ++c) {
                short8 b = *(const short8*)&Whb[(size_t)(16 * cg2 + r16) * 64 + 32 * c + quad * 8];
                acc2 = __builtin_amdgcn_mfma_f32_16x16x32_bf16(a2[c], b, acc2, 0, 0, 0);
            }

#pragma unroll
            for (int r = 0; r < 4; ++r) {
                const int mm = m0 + 16 * rg + quad * 4 + r;
                if (mm >= n) continue;
                const int o = 16 * cg2 + r16;
                float v = acc2[r] + hbias[o];
                if (o < 64)      nev[(size_t)mm * 64 + o] = v;
                else if (o < 74) cls[(size_t)mm * 10 + (o - 64)] = v;
            }
        }
    }
}

// ---------------- launch ----------------

extern "C" void kernel_launch(void* const* d_in, const int* in_sizes, int n_in,
                              void* d_out, int out_size, void* d_ws, size_t ws_size,
                              hipStream_t stream) {
    const float* x  = (const float*)d_in[0];
    const int*   ei = (const int*)d_in[1];
    const float* W1 = (const float*)d_in[2];
    const float* b1 = (const float*)d_in[3];
    const float* W2 = (const float*)d_in[4];
    const float* b2 = (const float*)d_in[5];
    const float* W3 = (const float*)d_in[6];
    const float* b3 = (const float*)d_in[7];
    const float* Wp = (const float*)d_in[8];
    const float* bp = (const float*)d_in[9];
    const float* Wc = (const float*)d_in[10];
    const float* bc = (const float*)d_in[11];

    const int n = in_sizes[0] / 64;   // 50000
    const int E = in_sizes[1] / 2;    // 800000
    const int* src = ei;
    const int* dst = ei + E;

    const int nScanBlocks = (n + 255) / 256;   // 196

    // workspace layout
    int* deg       = (int*)d_ws;              // n
    int* offsets   = deg + n;                 // n+1
    int* cursor    = offsets + (n + 1);       // n
    int* partial   = cursor + n;              // 256
    unsigned short* csr_src = (unsigned short*)(partial + 256);   // E u16
    uintptr_t p = (uintptr_t)(csr_src + E);
    p = (p + 255) & ~(uintptr_t)255;
    unsigned int* Hb  = (unsigned int*)p;          // n*64 (n x 128 bf16)
    unsigned int* Yb  = Hb + (size_t)n * 64;       // n*64 (n x 128 bf16)
    unsigned int* xb  = Yb + (size_t)n * 64;       // n*32 (n x 64 bf16)
    unsigned int* W1b = xb + (size_t)n * 32;       // 4096 uints
    unsigned int* W2b = W1b + 4096;                // 8192
    unsigned int* W3b = W2b + 8192;                // 4096
    unsigned int* Whb = W3b + 4096;                // 2560
    float* hbias = (float*)(Whb + 2560);           // 80

    float* out_emb = (float*)d_out;
    float* out_nev = out_emb + (size_t)n * 64;
    float* out_cls = out_nev + (size_t)n * 64;

    hipMemsetAsync(deg, 0, (size_t)n * sizeof(int), stream);

    const int nCnt = 256;
    const int convTotal = n * 32 + 4096 + 8192 + 4096 + 2560 + 80;
    const int convBlocks = (convTotal + 255) / 256;
    prep_kernel<<<nCnt + convBlocks, 256, 0, stream>>>(
        dst, deg, E, nCnt,
        x, W1, W2, W3, Wp, bp, Wc, bc, xb, W1b, W2b, W3b, Whb, hbias, n * 32);

    partial_sum_kernel<<<nScanBlocks, 256, 0, stream>>>(deg, partial, n);
    local_scan_kernel<<<nScanBlocks, 256, 0, stream>>>(deg, partial, offsets, cursor, nScanBlocks, n);

    scatter_kernel<<<1024, 256, 0, stream>>>(src, dst, cursor, csr_src, E);

    const int gF = (n + 31) / 32;    // 1563 blocks, 512 threads

    // layer 1: agg(x, F=64) + GEMM 64->128 -> Hb (bf16)
    fused_agg_gemm_kernel<64, 128, 0><<<gF, 512, 0, stream>>>(
        (const unsigned long long*)xb, offsets, csr_src,
        (const unsigned short*)W1b, b1, (unsigned short*)Hb,
        nullptr, nullptr, nullptr, nullptr, nullptr, n);

    // layer 2: agg(Hb, F=128) + GEMM 128->128 -> Yb (bf16)
    fused_agg_gemm_kernel<128, 128, 0><<<gF, 512, 0, stream>>>(
        (const unsigned long long*)Hb, offsets, csr_src,
        (const unsigned short*)W2b, b2, (unsigned short*)Yb,
        nullptr, nullptr, nullptr, nullptr, nullptr, n);

    // layer 3: agg(Yb, F=128) + GEMM 128->64 + heads -> out_emb / nev / cls
    fused_agg_gemm_kernel<128, 64, 3><<<gF, 512, 0, stream>>>(
        (const unsigned long long*)Yb, offsets, csr_src,
        (const unsigned short*)W3b, b3, nullptr,
        out_emb, out_nev, out_cls, (const unsigned short*)Whb, hbias, n);
}

// Round 4
// 292.367 us; speedup vs baseline: 1.0729x; 1.0174x over previous
//
#include <hip/hip_runtime.h>
#include <hip/hip_bf16.h>

typedef __attribute__((ext_vector_type(8))) short short8;
typedef __attribute__((ext_vector_type(4))) float floatx4;

__device__ __forceinline__ float bf_lo(unsigned int u) { return __uint_as_float(u << 16); }
__device__ __forceinline__ float bf_hi(unsigned int u) { return __uint_as_float(u & 0xffff0000u); }

__device__ __forceinline__ unsigned short f2bf_rne(float f) {
    unsigned u = __float_as_uint(f);
    unsigned rb = (u >> 16) & 1u;
    u += 0x7fffu + rb;
    return (unsigned short)(u >> 16);
}
__device__ __forceinline__ unsigned int pack_bf2(float x, float y) {
    return (unsigned int)f2bf_rne(x) | ((unsigned int)f2bf_rne(y) << 16);
}

__device__ __forceinline__ void acc4(unsigned long long v, float& f0, float& f1, float& f2, float& f3) {
    unsigned ua = (unsigned)v, ub = (unsigned)(v >> 32);
    f0 += bf_lo(ua); f1 += bf_hi(ua); f2 += bf_lo(ub); f3 += bf_hi(ub);
}

// ---------------- prep: deg-count (blocks [0,nCnt)) + convert/pack (rest) ----------------
// deg pre-zeroed by memset. Count atomics are non-returning (fire-and-forget) — cheap.

__global__ __launch_bounds__(256) void prep_kernel(const int* __restrict__ dst,
                                                   int* __restrict__ deg, int E, int nCnt,
                                                   const float* __restrict__ x,
                                                   const float* __restrict__ W1,
                                                   const float* __restrict__ W2,
                                                   const float* __restrict__ W3,
                                                   const float* __restrict__ Wp, const float* __restrict__ bp,
                                                   const float* __restrict__ Wc, const float* __restrict__ bc,
                                                   unsigned int* __restrict__ xb,
                                                   unsigned int* __restrict__ W1b,
                                                   unsigned int* __restrict__ W2b,
                                                   unsigned int* __restrict__ W3b,
                                                   unsigned int* __restrict__ Whb,
                                                   float* __restrict__ hbias,
                                                   int nx) {
    if ((int)blockIdx.x < nCnt) {
        const int chunk = (E + nCnt - 1) / nCnt;
        const int lo = blockIdx.x * chunk;
        const int hi = min(lo + chunk, E);
        for (int e = lo + threadIdx.x; e < hi; e += 256)
            atomicAdd(&deg[dst[e]], 1);
        return;
    }
    int i = (blockIdx.x - nCnt) * 256 + threadIdx.x;
    const int T0 = nx;            // x pairs
    const int T1 = T0 + 4096;     // W1 128x64
    const int T2 = T1 + 8192;     // W2 128x128
    const int T3 = T2 + 4096;     // W3 64x128
    const int T4 = T3 + 2560;     // Whb 80x64
    const int T5 = T4 + 80;       // hbias
    if (i < T0) {
        float2 f = ((const float2*)x)[i];
        xb[i] = pack_bf2(f.x, f.y);
    } else if (i < T1) {
        float2 f = ((const float2*)W1)[i - T0];
        W1b[i - T0] = pack_bf2(f.x, f.y);
    } else if (i < T2) {
        float2 f = ((const float2*)W2)[i - T1];
        W2b[i - T1] = pack_bf2(f.x, f.y);
    } else if (i < T3) {
        float2 f = ((const float2*)W3)[i - T2];
        W3b[i - T2] = pack_bf2(f.x, f.y);
    } else if (i < T4) {
        int j = i - T3;
        int r = j >> 5, c = (j & 31) * 2;
        float v0 = 0.f, v1 = 0.f;
        if (r < 64)      { v0 = Wp[r * 64 + c]; v1 = Wp[r * 64 + c + 1]; }
        else if (r < 74) { v0 = Wc[(r - 64) * 64 + c]; v1 = Wc[(r - 64) * 64 + c + 1]; }
        Whb[j] = pack_bf2(v0, v1);
    } else if (i < T5) {
        int j = i - T4;
        float v = 0.f;
        if (j < 64)      v = bp[j];
        else if (j < 74) v = bc[j - 64];
        hbias[j] = v;
    }
}

// XCD-sharded filter scatter: shard = (dst>>8)&7 matched to XCD via blockIdx&7.
// Each block reads its 1/nSub chunk of the edge list and handles only its shard's
// edges, so the RETURNING cursor atomics and csr stores stay in one XCD's L2
// (cursor runs are 1KB-aligned per shard; no cross-die line ping-pong).
__global__ __launch_bounds__(256) void scatter_kernel(const int* __restrict__ src,
                                                      const int* __restrict__ dst,
                                                      int* __restrict__ cursor,
                                                      unsigned short* __restrict__ csr_src,
                                                      int E, int nSub) {
    const int s   = blockIdx.x & 7;
    const int sub = blockIdx.x >> 3;
    const int per = (E + nSub - 1) / nSub;
    const int lo  = sub * per;
    const int hi  = min(lo + per, E);
    for (int i = lo + threadIdx.x; i < hi; i += 256) {
        int d = dst[i];
        if (((d >> 8) & 7) == s) {
            int pos = atomicAdd(&cursor[d], 1);
            csr_src[pos] = (unsigned short)src[i];
        }
    }
}

// ---------------- scan ----------------

__global__ __launch_bounds__(256) void partial_sum_kernel(const int* __restrict__ deg,
                                                          int* __restrict__ partial, int n) {
    __shared__ int s[256];
    int t = threadIdx.x;
    int i = blockIdx.x * 256 + t;
    s[t] = (i < n) ? deg[i] : 0;
    __syncthreads();
    for (int off = 128; off > 0; off >>= 1) {
        if (t < off) s[t] += s[t + off];
        __syncthreads();
    }
    if (t == 0) partial[blockIdx.x] = s[0];
}

__global__ __launch_bounds__(256) void local_scan_kernel(const int* __restrict__ deg,
                                                         const int* __restrict__ partial,
                                                         int* __restrict__ offsets,
                                                         int* __restrict__ cursor, int nblocks, int n) {
    __shared__ int sp[256];
    __shared__ int s[256];
    int t = threadIdx.x;
    sp[t] = (t < nblocks) ? partial[t] : 0;
    __syncthreads();
    for (int off = 1; off < 256; off <<= 1) {
        int u = (t >= off) ? sp[t - off] : 0;
        __syncthreads();
        sp[t] += u;
        __syncthreads();
    }
    const int blockbase = (blockIdx.x == 0) ? 0 : sp[blockIdx.x - 1];
    if (blockIdx.x == 0 && t == 0) offsets[n] = sp[nblocks - 1];

    int i = blockIdx.x * 256 + t;
    int v = (i < n) ? deg[i] : 0;
    s[t] = v;
    __syncthreads();
    for (int off = 1; off < 256; off <<= 1) {
        int u = (t >= off) ? s[t - off] : 0;
        __syncthreads();
        s[t] += u;
        __syncthreads();
    }
    if (i < n) {
        int o = blockbase + s[t] - v;
        offsets[i] = o;
        cursor[i]  = o;
    }
}

// ---------------- Fused agg + MFMA GEMM per layer ----------------
// Block = 512 threads (8 waves), 32 nodes. Phase A: each wave aggregates 4 nodes
// into an LDS tile; cascaded batch depths keep gathers in flight (bit-identical
// accumulation order). Phase B: 8 waves MFMA the 32xF_OUT tile from LDS.
// MODE 0: bf16 out + relu.  MODE 3: relu, fp32 emb out, heads MFMA via LDS Ytile.

template <int F_IN, int F_OUT, int MODE>
__global__ __launch_bounds__(512) void fused_agg_gemm_kernel(
        const unsigned long long* __restrict__ xt,      // gather table, F_IN/4 u64 per row
        const int* __restrict__ offsets,
        const unsigned short* __restrict__ csr_src,
        const unsigned short* __restrict__ Wb,          // F_OUT x F_IN bf16
        const float* __restrict__ bias,
        unsigned short* __restrict__ Yb,                // MODE 0 out
        float* __restrict__ Yf,                         // MODE 3: emb out (fp32)
        float* __restrict__ nev, float* __restrict__ cls,
        const unsigned short* __restrict__ Whb, const float* __restrict__ hbias,
        int n) {
    constexpr int KC   = F_IN / 32;     // short8 chunks per row
    constexpr int XSTR = F_IN / 4;      // u64 per gather-table row
    constexpr int HSTR = F_IN + 8;      // LDS row stride (shorts), breaks pow2 banks
    __shared__ __align__(16) unsigned short Ht[32 * HSTR];
    __shared__ __align__(16) unsigned short Yt[(MODE == 3) ? 32 * 72 : 16];

    const int lane = threadIdx.x & 63;
    const int wv   = threadIdx.x >> 6;      // 0..7
    const int m0   = blockIdx.x * 32;

    // ---------- Phase A: aggregation, 4 nodes per wave ----------
    if (F_IN == 64) {
        const int quad = lane >> 4;
        const int c    = lane & 15;
#pragma unroll 1
        for (int i = 0; i < 4; ++i) {
            const int row  = wv * 4 + i;
            const int node = m0 + row;
            if (node < n) {
                const int start = offsets[node];
                const int end   = offsets[node + 1];
                float s0 = 0.f, s1 = 0.f, s2 = 0.f, s3 = 0.f;
                int e = start;
                while (e < end) {
                    int cnt = min(64, end - e);
                    int ii = e + lane; if (ii >= end) ii = end - 1;
                    int idx = csr_src[ii];
                    int j = 0;
                    for (; j + 32 <= cnt; j += 32) {
                        unsigned long long v[8];
#pragma unroll
                        for (int q = 0; q < 8; ++q) {
                            int nb = __shfl(idx, j + q * 4 + quad, 64);
                            v[q] = xt[(size_t)nb * XSTR + c];
                        }
#pragma unroll
                        for (int q = 0; q < 8; ++q) acc4(v[q], s0, s1, s2, s3);
                    }
                    if (j + 16 <= cnt) {
                        unsigned long long v[4];
#pragma unroll
                        for (int q = 0; q < 4; ++q) {
                            int nb = __shfl(idx, j + q * 4 + quad, 64);
                            v[q] = xt[(size_t)nb * XSTR + c];
                        }
#pragma unroll
                        for (int q = 0; q < 4; ++q) acc4(v[q], s0, s1, s2, s3);
                        j += 16;
                    }
                    if (j + 8 <= cnt) {
                        unsigned long long v[2];
#pragma unroll
                        for (int q = 0; q < 2; ++q) {
                            int nb = __shfl(idx, j + q * 4 + quad, 64);
                            v[q] = xt[(size_t)nb * XSTR + c];
                        }
#pragma unroll
                        for (int q = 0; q < 2; ++q) acc4(v[q], s0, s1, s2, s3);
                        j += 8;
                    }
                    if (j + 4 <= cnt) {
                        int nb = __shfl(idx, j + quad, 64);
                        acc4(xt[(size_t)nb * XSTR + c], s0, s1, s2, s3);
                        j += 4;
                    }
                    int rem = cnt - j;
                    if (rem > 0) {                         // wave-uniform
                        int sl = j + quad;
                        sl = (sl < cnt) ? sl : (cnt - 1);  // keep source lane active
                        int nb = __shfl(idx, sl, 64);      // all lanes execute
                        if (quad < rem) acc4(xt[(size_t)nb * XSTR + c], s0, s1, s2, s3);
                    }
                    e += cnt;
                }
                s0 += __shfl(s0, lane ^ 16, 64); s1 += __shfl(s1, lane ^ 16, 64);
                s2 += __shfl(s2, lane ^ 16, 64); s3 += __shfl(s3, lane ^ 16, 64);
                s0 += __shfl(s0, lane ^ 32, 64); s1 += __shfl(s1, lane ^ 32, 64);
                s2 += __shfl(s2, lane ^ 32, 64); s3 += __shfl(s3, lane ^ 32, 64);
                if (quad == 0) {
                    float inv = 1.0f / fmaxf((float)(end - start), 1.0f);
                    unsigned long long sv = xt[(size_t)node * XSTR + c];
                    unsigned ua = (unsigned)sv, ub = (unsigned)(sv >> 32);
                    unsigned o0 = pack_bf2(s0 * inv + bf_lo(ua), s1 * inv + bf_hi(ua));
                    unsigned o1 = pack_bf2(s2 * inv + bf_lo(ub), s3 * inv + bf_hi(ub));
                    *(unsigned long long*)&Ht[row * HSTR + c * 4] =
                        ((unsigned long long)o1 << 32) | o0;
                }
            } else if (quad == 0) {
                *(unsigned long long*)&Ht[row * HSTR + c * 4] = 0ull;
            }
        }
    } else {
        const int half = lane >> 5;
        const int c    = lane & 31;
#pragma unroll 1
        for (int i = 0; i < 4; ++i) {
            const int row  = wv * 4 + i;
            const int node = m0 + row;
            if (node < n) {
                const int start = offsets[node];
                const int end   = offsets[node + 1];
                float s0 = 0.f, s1 = 0.f, s2 = 0.f, s3 = 0.f;
                int e = start;
                while (e < end) {
                    int cnt = min(64, end - e);
                    int ii = e + lane; if (ii >= end) ii = end - 1;
                    int idx = csr_src[ii];
                    int j = 0;
                    for (; j + 16 <= cnt; j += 16) {
                        unsigned long long v[8];
#pragma unroll
                        for (int q = 0; q < 8; ++q) {
                            int nb = __shfl(idx, j + q * 2 + half, 64);
                            v[q] = xt[(size_t)nb * XSTR + c];
                        }
#pragma unroll
                        for (int q = 0; q < 8; ++q) acc4(v[q], s0, s1, s2, s3);
                    }
                    if (j + 8 <= cnt) {
                        unsigned long long v[4];
#pragma unroll
                        for (int q = 0; q < 4; ++q) {
                            int nb = __shfl(idx, j + q * 2 + half, 64);
                            v[q] = xt[(size_t)nb * XSTR + c];
                        }
#pragma unroll
                        for (int q = 0; q < 4; ++q) acc4(v[q], s0, s1, s2, s3);
                        j += 8;
                    }
                    if (j + 4 <= cnt) {
                        unsigned long long v[2];
#pragma unroll
                        for (int q = 0; q < 2; ++q) {
                            int nb = __shfl(idx, j + q * 2 + half, 64);
                            v[q] = xt[(size_t)nb * XSTR + c];
                        }
#pragma unroll
                        for (int q = 0; q < 2; ++q) acc4(v[q], s0, s1, s2, s3);
                        j += 4;
                    }
                    if (j + 2 <= cnt) {
                        int nb = __shfl(idx, j + half, 64);
                        acc4(xt[(size_t)nb * XSTR + c], s0, s1, s2, s3);
                        j += 2;
                    }
                    if (j < cnt) {                         // wave-uniform, rem == 1
                        int nb = __shfl(idx, j, 64);       // all lanes execute
                        if (half == 0) acc4(xt[(size_t)nb * XSTR + c], s0, s1, s2, s3);
                    }
                    e += cnt;
                }
                s0 += __shfl(s0, lane ^ 32, 64); s1 += __shfl(s1, lane ^ 32, 64);
                s2 += __shfl(s2, lane ^ 32, 64); s3 += __shfl(s3, lane ^ 32, 64);
                if (half == 0) {
                    float inv = 1.0f / fmaxf((float)(end - start), 1.0f);
                    unsigned long long sv = xt[(size_t)node * XSTR + c];
                    unsigned ua = (unsigned)sv, ub = (unsigned)(sv >> 32);
                    unsigned o0 = pack_bf2(s0 * inv + bf_lo(ua), s1 * inv + bf_hi(ua));
                    unsigned o1 = pack_bf2(s2 * inv + bf_lo(ub), s3 * inv + bf_hi(ub));
                    *(unsigned long long*)&Ht[row * HSTR + c * 4] =
                        ((unsigned long long)o1 << 32) | o0;
                }
            } else if (half == 0) {
                *(unsigned long long*)&Ht[row * HSTR + c * 4] = 0ull;
            }
        }
    }
    __syncthreads();

    // ---------- Phase B: MFMA on the 32-row tile ----------
    const int quad = lane >> 4;
    const int r16  = lane & 15;

    if (MODE == 0) {
        // 32 x F_OUT(=128): 2 row-groups x 8 col-groups = 16 tiles, 2 per wave
        const int rowg = wv & 1;
        const int cg0  = (wv >> 1) * 2;
        short8 a[KC];
#pragma unroll
        for (int c = 0; c < KC; ++c)
            a[c] = *(const short8*)&Ht[(16 * rowg + r16) * HSTR + 32 * c + quad * 8];

        floatx4 acc[2];
#pragma unroll
        for (int j = 0; j < 2; ++j)
#pragma unroll
            for (int r = 0; r < 4; ++r) acc[j][r] = 0.f;

#pragma unroll
        for (int j = 0; j < 2; ++j)
#pragma unroll
            for (int c = 0; c < KC; ++c) {
                short8 b = *(const short8*)&Wb[(size_t)(16 * (cg0 + j) + r16) * F_IN + 32 * c + quad * 8];
                acc[j] = __builtin_amdgcn_mfma_f32_16x16x32_bf16(a[c], b, acc[j], 0, 0, 0);
            }

#pragma unroll
        for (int r = 0; r < 4; ++r) {
            const int mm = m0 + 16 * rowg + quad * 4 + r;
            if (mm >= n) continue;
#pragma unroll
            for (int j = 0; j < 2; ++j) {
                const int o = 16 * (cg0 + j) + r16;
                Yb[(size_t)mm * F_OUT + o] = f2bf_rne(fmaxf(acc[j][r] + bias[o], 0.f));
            }
        }
    } else {
        // layer3: 32 x 64 = 2 x 4 tiles, 1 per wave; then heads from LDS Ytile
        const int rowg = wv & 1;
        const int cg   = wv >> 1;      // 0..3
        short8 a[KC];
#pragma unroll
        for (int c = 0; c < KC; ++c)
            a[c] = *(const short8*)&Ht[(16 * rowg + r16) * HSTR + 32 * c + quad * 8];

        floatx4 acc;
#pragma unroll
        for (int r = 0; r < 4; ++r) acc[r] = 0.f;

#pragma unroll
        for (int c = 0; c < KC; ++c) {
            short8 b = *(const short8*)&Wb[(size_t)(16 * cg + r16) * F_IN + 32 * c + quad * 8];
            acc = __builtin_amdgcn_mfma_f32_16x16x32_bf16(a[c], b, acc, 0, 0, 0);
        }

#pragma unroll
        for (int r = 0; r < 4; ++r) {
            const int lr = 16 * rowg + quad * 4 + r;
            const int mm = m0 + lr;
            const int o  = 16 * cg + r16;
            if (mm < n) {
                float v = fmaxf(acc[r] + bias[o], 0.f);
                Yf[(size_t)mm * 64 + o] = v;
                Yt[lr * 72 + o] = f2bf_rne(v);
            } else {
                Yt[lr * 72 + o] = 0;
            }
        }
        __syncthreads();

        // heads: 32 x 80 = 2 x 5 tiles = 10, waves 0..7 take t=wv, waves 0..1 also t=8+wv
        for (int t = wv; t < 10; t += 8) {
            const int rg  = t & 1;
            const int cg2 = t >> 1;    // 0..4
            short8 a2[2];
#pragma unroll
            for (int c = 0; c < 2; ++c)
                a2[c] = *(const short8*)&Yt[(16 * rg + r16) * 72 + 32 * c + quad * 8];

            floatx4 acc2;
#pragma unroll
            for (int r = 0; r < 4; ++r) acc2[r] = 0.f;

#pragma unroll
            for (int c = 0; c < 2; ++c) {
                short8 b = *(const short8*)&Whb[(size_t)(16 * cg2 + r16) * 64 + 32 * c + quad * 8];
                acc2 = __builtin_amdgcn_mfma_f32_16x16x32_bf16(a2[c], b, acc2, 0, 0, 0);
            }

#pragma unroll
            for (int r = 0; r < 4; ++r) {
                const int mm = m0 + 16 * rg + quad * 4 + r;
                if (mm >= n) continue;
                const int o = 16 * cg2 + r16;
                float v = acc2[r] + hbias[o];
                if (o < 64)      nev[(size_t)mm * 64 + o] = v;
                else if (o < 74) cls[(size_t)mm * 10 + (o - 64)] = v;
            }
        }
    }
}

// ---------------- launch ----------------

extern "C" void kernel_launch(void* const* d_in, const int* in_sizes, int n_in,
                              void* d_out, int out_size, void* d_ws, size_t ws_size,
                              hipStream_t stream) {
    const float* x  = (const float*)d_in[0];
    const int*   ei = (const int*)d_in[1];
    const float* W1 = (const float*)d_in[2];
    const float* b1 = (const float*)d_in[3];
    const float* W2 = (const float*)d_in[4];
    const float* b2 = (const float*)d_in[5];
    const float* W3 = (const float*)d_in[6];
    const float* b3 = (const float*)d_in[7];
    const float* Wp = (const float*)d_in[8];
    const float* bp = (const float*)d_in[9];
    const float* Wc = (const float*)d_in[10];
    const float* bc = (const float*)d_in[11];

    const int n = in_sizes[0] / 64;   // 50000
    const int E = in_sizes[1] / 2;    // 800000
    const int* src = ei;
    const int* dst = ei + E;

    const int nScanBlocks = (n + 255) / 256;   // 196

    // workspace layout
    int* deg       = (int*)d_ws;              // n
    int* offsets   = deg + n;                 // n+1
    int* cursor    = offsets + (n + 1);       // n
    int* partial   = cursor + n;              // 256
    unsigned short* csr_src = (unsigned short*)(partial + 256);   // E u16
    uintptr_t p = (uintptr_t)(csr_src + E);
    p = (p + 255) & ~(uintptr_t)255;
    unsigned int* Hb  = (unsigned int*)p;          // n*64 (n x 128 bf16)
    unsigned int* Yb  = Hb + (size_t)n * 64;       // n*64 (n x 128 bf16)
    unsigned int* xb  = Yb + (size_t)n * 64;       // n*32 (n x 64 bf16)
    unsigned int* W1b = xb + (size_t)n * 32;       // 4096 uints
    unsigned int* W2b = W1b + 4096;                // 8192
    unsigned int* W3b = W2b + 8192;                // 4096
    unsigned int* Whb = W3b + 4096;                // 2560
    float* hbias = (float*)(Whb + 2560);           // 80

    float* out_emb = (float*)d_out;
    float* out_nev = out_emb + (size_t)n * 64;
    float* out_cls = out_nev + (size_t)n * 64;

    hipMemsetAsync(deg, 0, (size_t)n * sizeof(int), stream);

    const int nCnt = 256;
    const int convTotal = n * 32 + 4096 + 8192 + 4096 + 2560 + 80;
    const int convBlocks = (convTotal + 255) / 256;
    prep_kernel<<<nCnt + convBlocks, 256, 0, stream>>>(
        dst, deg, E, nCnt,
        x, W1, W2, W3, Wp, bp, Wc, bc, xb, W1b, W2b, W3b, Whb, hbias, n * 32);

    partial_sum_kernel<<<nScanBlocks, 256, 0, stream>>>(deg, partial, n);
    local_scan_kernel<<<nScanBlocks, 256, 0, stream>>>(deg, partial, offsets, cursor, nScanBlocks, n);

    const int nSub = 128;   // 8 shards x 128 subs = 1024 blocks
    scatter_kernel<<<8 * nSub, 256, 0, stream>>>(src, dst, cursor, csr_src, E, nSub);

    const int gF = (n + 31) / 32;    // 1563 blocks, 512 threads

    // layer 1: agg(x, F=64) + GEMM 64->128 -> Hb (bf16)
    fused_agg_gemm_kernel<64, 128, 0><<<gF, 512, 0, stream>>>(
        (const unsigned long long*)xb, offsets, csr_src,
        (const unsigned short*)W1b, b1, (unsigned short*)Hb,
        nullptr, nullptr, nullptr, nullptr, nullptr, n);

    // layer 2: agg(Hb, F=128) + GEMM 128->128 -> Yb (bf16)
    fused_agg_gemm_kernel<128, 128, 0><<<gF, 512, 0, stream>>>(
        (const unsigned long long*)Hb, offsets, csr_src,
        (const unsigned short*)W2b, b2, (unsigned short*)Yb,
        nullptr, nullptr, nullptr, nullptr, nullptr, n);

    // layer 3: agg(Yb, F=128) + GEMM 128->64 + heads -> out_emb / nev / cls
    fused_agg_gemm_kernel<128, 64, 3><<<gF, 512, 0, stream>>>(
        (const unsigned long long*)Yb, offsets, csr_src,
        (const unsigned short*)W3b, b3, nullptr,
        out_emb, out_nev, out_cls, (const unsigned short*)Whb, hbias, n);
}

// Round 5
// 284.767 us; speedup vs baseline: 1.1016x; 1.0267x over previous
//
#include <hip/hip_runtime.h>
#include <hip/hip_bf16.h>

typedef __attribute__((ext_vector_type(8))) short short8;
typedef __attribute__((ext_vector_type(4))) float floatx4;

__device__ __forceinline__ float bf_lo(unsigned int u) { return __uint_as_float(u << 16); }
__device__ __forceinline__ float bf_hi(unsigned int u) { return __uint_as_float(u & 0xffff0000u); }

__device__ __forceinline__ unsigned short f2bf_rne(float f) {
    unsigned u = __float_as_uint(f);
    unsigned rb = (u >> 16) & 1u;
    u += 0x7fffu + rb;
    return (unsigned short)(u >> 16);
}
__device__ __forceinline__ unsigned int pack_bf2(float x, float y) {
    return (unsigned int)f2bf_rne(x) | ((unsigned int)f2bf_rne(y) << 16);
}

__device__ __forceinline__ void acc4(unsigned long long v, float& f0, float& f1, float& f2, float& f3) {
    unsigned ua = (unsigned)v, ub = (unsigned)(v >> 32);
    f0 += bf_lo(ua); f1 += bf_hi(ua); f2 += bf_lo(ub); f3 += bf_hi(ub);
}

// ---------------- prep: deg-count (blocks [0,nCnt)) + convert/pack (rest) ----------------

__global__ __launch_bounds__(256) void prep_kernel(const int* __restrict__ dst,
                                                   int* __restrict__ deg, int E, int nCnt,
                                                   const float* __restrict__ x,
                                                   const float* __restrict__ W1,
                                                   const float* __restrict__ W2,
                                                   const float* __restrict__ W3,
                                                   const float* __restrict__ Wp, const float* __restrict__ bp,
                                                   const float* __restrict__ Wc, const float* __restrict__ bc,
                                                   unsigned int* __restrict__ xb,
                                                   unsigned int* __restrict__ W1b,
                                                   unsigned int* __restrict__ W2b,
                                                   unsigned int* __restrict__ W3b,
                                                   unsigned int* __restrict__ Whb,
                                                   float* __restrict__ hbias,
                                                   int nx) {
    if ((int)blockIdx.x < nCnt) {
        const int chunk = (E + nCnt - 1) / nCnt;
        const int lo = blockIdx.x * chunk;
        const int hi = min(lo + chunk, E);
        for (int e = lo + threadIdx.x; e < hi; e += 256)
            atomicAdd(&deg[dst[e]], 1);
        return;
    }
    int i = (blockIdx.x - nCnt) * 256 + threadIdx.x;
    const int T0 = nx;            // x pairs
    const int T1 = T0 + 4096;     // W1 128x64
    const int T2 = T1 + 8192;     // W2 128x128
    const int T3 = T2 + 4096;     // W3 64x128
    const int T4 = T3 + 2560;     // Whb 80x64
    const int T5 = T4 + 80;       // hbias
    if (i < T0) {
        float2 f = ((const float2*)x)[i];
        xb[i] = pack_bf2(f.x, f.y);
    } else if (i < T1) {
        float2 f = ((const float2*)W1)[i - T0];
        W1b[i - T0] = pack_bf2(f.x, f.y);
    } else if (i < T2) {
        float2 f = ((const float2*)W2)[i - T1];
        W2b[i - T1] = pack_bf2(f.x, f.y);
    } else if (i < T3) {
        float2 f = ((const float2*)W3)[i - T2];
        W3b[i - T2] = pack_bf2(f.x, f.y);
    } else if (i < T4) {
        int j = i - T3;
        int r = j >> 5, c = (j & 31) * 2;
        float v0 = 0.f, v1 = 0.f;
        if (r < 64)      { v0 = Wp[r * 64 + c]; v1 = Wp[r * 64 + c + 1]; }
        else if (r < 74) { v0 = Wc[(r - 64) * 64 + c]; v1 = Wc[(r - 64) * 64 + c + 1]; }
        Whb[j] = pack_bf2(v0, v1);
    } else if (i < T5) {
        int j = i - T4;
        float v = 0.f;
        if (j < 64)      v = bp[j];
        else if (j < 74) v = bc[j - 64];
        hbias[j] = v;
    }
}

// XCD-sharded filter scatter: shard = (dst>>8)&7 matched to XCD via blockIdx&7.
__global__ __launch_bounds__(256) void scatter_kernel(const int* __restrict__ src,
                                                      const int* __restrict__ dst,
                                                      int* __restrict__ cursor,
                                                      unsigned short* __restrict__ csr_src,
                                                      int E, int nSub) {
    const int s   = blockIdx.x & 7;
    const int sub = blockIdx.x >> 3;
    const int per = (E + nSub - 1) / nSub;
    const int lo  = sub * per;
    const int hi  = min(lo + per, E);
    for (int i = lo + threadIdx.x; i < hi; i += 256) {
        int d = dst[i];
        if (((d >> 8) & 7) == s) {
            int pos = atomicAdd(&cursor[d], 1);
            csr_src[pos] = (unsigned short)src[i];
        }
    }
}

// ---------------- scan ----------------

__global__ __launch_bounds__(256) void partial_sum_kernel(const int* __restrict__ deg,
                                                          int* __restrict__ partial, int n) {
    __shared__ int s[256];
    int t = threadIdx.x;
    int i = blockIdx.x * 256 + t;
    s[t] = (i < n) ? deg[i] : 0;
    __syncthreads();
    for (int off = 128; off > 0; off >>= 1) {
        if (t < off) s[t] += s[t + off];
        __syncthreads();
    }
    if (t == 0) partial[blockIdx.x] = s[0];
}

__global__ __launch_bounds__(256) void local_scan_kernel(const int* __restrict__ deg,
                                                         const int* __restrict__ partial,
                                                         int* __restrict__ offsets,
                                                         int* __restrict__ cursor, int nblocks, int n) {
    __shared__ int sp[256];
    __shared__ int s[256];
    int t = threadIdx.x;
    sp[t] = (t < nblocks) ? partial[t] : 0;
    __syncthreads();
    for (int off = 1; off < 256; off <<= 1) {
        int u = (t >= off) ? sp[t - off] : 0;
        __syncthreads();
        sp[t] += u;
        __syncthreads();
    }
    const int blockbase = (blockIdx.x == 0) ? 0 : sp[blockIdx.x - 1];
    if (blockIdx.x == 0 && t == 0) offsets[n] = sp[nblocks - 1];

    int i = blockIdx.x * 256 + t;
    int v = (i < n) ? deg[i] : 0;
    s[t] = v;
    __syncthreads();
    for (int off = 1; off < 256; off <<= 1) {
        int u = (t >= off) ? s[t - off] : 0;
        __syncthreads();
        s[t] += u;
        __syncthreads();
    }
    if (i < n) {
        int o = blockbase + s[t] - v;
        offsets[i] = o;
        cursor[i]  = o;
    }
}

// ---------------- Fused agg + MFMA GEMM per layer ----------------
// Block = 512 threads (8 waves), 32 nodes. Phase A: each wave aggregates 4 nodes
// (static rows wv*4+i) with a 2-deep SCALAR-ROTATION software pipeline:
//   iteration i issues offsets loads for node i+2 and the first csr chunk for node
//   i+1 (whose offsets arrived last iteration), then processes node i whose csr
//   indices are already in registers. Self-row load hoisted above the gather loop.
// No arrays indexed by runtime i (rule: would spill to scratch); no LDS tickets.
// Accumulation order is bit-identical to the unpipelined version.
// Phase B: 8 waves MFMA the 32xF_OUT tile from LDS.
// MODE 0: bf16 out + relu.  MODE 3: relu, fp32 emb out, heads MFMA via LDS Ytile.

template <int F_IN, int F_OUT, int MODE>
__global__ __launch_bounds__(512) void fused_agg_gemm_kernel(
        const unsigned long long* __restrict__ xt,      // gather table, F_IN/4 u64 per row
        const int* __restrict__ offsets,
        const unsigned short* __restrict__ csr_src,
        const unsigned short* __restrict__ Wb,          // F_OUT x F_IN bf16
        const float* __restrict__ bias,
        unsigned short* __restrict__ Yb,                // MODE 0 out
        float* __restrict__ Yf,                         // MODE 3: emb out (fp32)
        float* __restrict__ nev, float* __restrict__ cls,
        const unsigned short* __restrict__ Whb, const float* __restrict__ hbias,
        int n) {
    constexpr int KC   = F_IN / 32;     // short8 chunks per row
    constexpr int XSTR = F_IN / 4;      // u64 per gather-table row
    constexpr int HSTR = F_IN + 8;      // LDS row stride (shorts), breaks pow2 banks
    __shared__ __align__(16) unsigned short Ht[32 * HSTR];
    __shared__ __align__(16) unsigned short Yt[(MODE == 3) ? 32 * 72 : 16];

    const int lane = threadIdx.x & 63;
    const int wv   = threadIdx.x >> 6;      // 0..7
    const int m0   = blockIdx.x * 32;

    // ---------- Phase A: aggregation, 4 nodes per wave, 2-deep pipeline ----------
    // pipeline state: A = current node range/csr, B = next node range
    int nsA = 0, neA = 0, nsB = 0, neB = 0, idxA = 0;
    {
        int nd = m0 + wv * 4;
        if (nd < n)     { nsA = offsets[nd];     neA = offsets[nd + 1]; }
        if (nd + 1 < n) { nsB = offsets[nd + 1]; neB = offsets[nd + 2]; }
    }
    if (neA > nsA) { int ii = nsA + lane; if (ii >= neA) ii = neA - 1; idxA = csr_src[ii]; }

    if (F_IN == 64) {
        const int quad = lane >> 4;
        const int c    = lane & 15;
#pragma unroll 1
        for (int i = 0; i < 4; ++i) {
            const int row  = wv * 4 + i;
            const int node = m0 + row;
            // prefetch offsets for node i+2 (independent)
            int nsC = 0, neC = 0;
            if (i < 2) {
                int nd = node + 2;
                if (nd < n) { nsC = offsets[nd]; neC = offsets[nd + 1]; }
            }
            // prefetch first csr chunk for node i+1 (offsets ready from last iter)
            int idxB = 0;
            if (neB > nsB) { int ii = nsB + lane; if (ii >= neB) ii = neB - 1; idxB = csr_src[ii]; }

            if (node < n) {
                unsigned long long sv = 0;
                if (quad == 0) sv = xt[(size_t)node * XSTR + c];   // hoisted self-row
                float s0 = 0.f, s1 = 0.f, s2 = 0.f, s3 = 0.f;
                int e = nsA;
                int idx = idxA;
                while (e < neA) {
                    int cnt = min(64, neA - e);
                    int j = 0;
                    for (; j + 32 <= cnt; j += 32) {
                        unsigned long long v[8];
#pragma unroll
                        for (int q = 0; q < 8; ++q) {
                            int nb = __shfl(idx, j + q * 4 + quad, 64);
                            v[q] = xt[(size_t)nb * XSTR + c];
                        }
#pragma unroll
                        for (int q = 0; q < 8; ++q) acc4(v[q], s0, s1, s2, s3);
                    }
                    if (j + 16 <= cnt) {
                        unsigned long long v[4];
#pragma unroll
                        for (int q = 0; q < 4; ++q) {
                            int nb = __shfl(idx, j + q * 4 + quad, 64);
                            v[q] = xt[(size_t)nb * XSTR + c];
                        }
#pragma unroll
                        for (int q = 0; q < 4; ++q) acc4(v[q], s0, s1, s2, s3);
                        j += 16;
                    }
                    if (j + 8 <= cnt) {
                        unsigned long long v[2];
#pragma unroll
                        for (int q = 0; q < 2; ++q) {
                            int nb = __shfl(idx, j + q * 4 + quad, 64);
                            v[q] = xt[(size_t)nb * XSTR + c];
                        }
#pragma unroll
                        for (int q = 0; q < 2; ++q) acc4(v[q], s0, s1, s2, s3);
                        j += 8;
                    }
                    if (j + 4 <= cnt) {
                        int nb = __shfl(idx, j + quad, 64);
                        acc4(xt[(size_t)nb * XSTR + c], s0, s1, s2, s3);
                        j += 4;
                    }
                    int rem = cnt - j;
                    if (rem > 0) {                         // wave-uniform
                        int sl = j + quad;
                        sl = (sl < cnt) ? sl : (cnt - 1);  // keep source lane active
                        int nb = __shfl(idx, sl, 64);      // all lanes execute
                        if (quad < rem) acc4(xt[(size_t)nb * XSTR + c], s0, s1, s2, s3);
                    }
                    e += cnt;
                    if (e < neA) { int ii = e + lane; if (ii >= neA) ii = neA - 1; idx = csr_src[ii]; }
                }
                s0 += __shfl(s0, lane ^ 16, 64); s1 += __shfl(s1, lane ^ 16, 64);
                s2 += __shfl(s2, lane ^ 16, 64); s3 += __shfl(s3, lane ^ 16, 64);
                s0 += __shfl(s0, lane ^ 32, 64); s1 += __shfl(s1, lane ^ 32, 64);
                s2 += __shfl(s2, lane ^ 32, 64); s3 += __shfl(s3, lane ^ 32, 64);
                if (quad == 0) {
                    float inv = 1.0f / fmaxf((float)(neA - nsA), 1.0f);
                    unsigned ua = (unsigned)sv, ub = (unsigned)(sv >> 32);
                    unsigned o0 = pack_bf2(s0 * inv + bf_lo(ua), s1 * inv + bf_hi(ua));
                    unsigned o1 = pack_bf2(s2 * inv + bf_lo(ub), s3 * inv + bf_hi(ub));
                    *(unsigned long long*)&Ht[row * HSTR + c * 4] =
                        ((unsigned long long)o1 << 32) | o0;
                }
            } else if (quad == 0) {
                *(unsigned long long*)&Ht[row * HSTR + c * 4] = 0ull;
            }
            // rotate pipeline
            nsA = nsB; neA = neB; idxA = idxB;
            nsB = nsC; neB = neC;
        }
    } else {
        const int half = lane >> 5;
        const int c    = lane & 31;
#pragma unroll 1
        for (int i = 0; i < 4; ++i) {
            const int row  = wv * 4 + i;
            const int node = m0 + row;
            int nsC = 0, neC = 0;
            if (i < 2) {
                int nd = node + 2;
                if (nd < n) { nsC = offsets[nd]; neC = offsets[nd + 1]; }
            }
            int idxB = 0;
            if (neB > nsB) { int ii = nsB + lane; if (ii >= neB) ii = neB - 1; idxB = csr_src[ii]; }

            if (node < n) {
                unsigned long long sv = 0;
                if (half == 0) sv = xt[(size_t)node * XSTR + c];   // hoisted self-row
                float s0 = 0.f, s1 = 0.f, s2 = 0.f, s3 = 0.f;
                int e = nsA;
                int idx = idxA;
                while (e < neA) {
                    int cnt = min(64, neA - e);
                    int j = 0;
                    for (; j + 16 <= cnt; j += 16) {
                        unsigned long long v[8];
#pragma unroll
                        for (int q = 0; q < 8; ++q) {
                            int nb = __shfl(idx, j + q * 2 + half, 64);
                            v[q] = xt[(size_t)nb * XSTR + c];
                        }
#pragma unroll
                        for (int q = 0; q < 8; ++q) acc4(v[q], s0, s1, s2, s3);
                    }
                    if (j + 8 <= cnt) {
                        unsigned long long v[4];
#pragma unroll
                        for (int q = 0; q < 4; ++q) {
                            int nb = __shfl(idx, j + q * 2 + half, 64);
                            v[q] = xt[(size_t)nb * XSTR + c];
                        }
#pragma unroll
                        for (int q = 0; q < 4; ++q) acc4(v[q], s0, s1, s2, s3);
                        j += 8;
                    }
                    if (j + 4 <= cnt) {
                        unsigned long long v[2];
#pragma unroll
                        for (int q = 0; q < 2; ++q) {
                            int nb = __shfl(idx, j + q * 2 + half, 64);
                            v[q] = xt[(size_t)nb * XSTR + c];
                        }
#pragma unroll
                        for (int q = 0; q < 2; ++q) acc4(v[q], s0, s1, s2, s3);
                        j += 4;
                    }
                    if (j + 2 <= cnt) {
                        int nb = __shfl(idx, j + half, 64);
                        acc4(xt[(size_t)nb * XSTR + c], s0, s1, s2, s3);
                        j += 2;
                    }
                    if (j < cnt) {                         // wave-uniform, rem == 1
                        int nb = __shfl(idx, j, 64);       // all lanes execute
                        if (half == 0) acc4(xt[(size_t)nb * XSTR + c], s0, s1, s2, s3);
                    }
                    e += cnt;
                    if (e < neA) { int ii = e + lane; if (ii >= neA) ii = neA - 1; idx = csr_src[ii]; }
                }
                s0 += __shfl(s0, lane ^ 32, 64); s1 += __shfl(s1, lane ^ 32, 64);
                s2 += __shfl(s2, lane ^ 32, 64); s3 += __shfl(s3, lane ^ 32, 64);
                if (half == 0) {
                    float inv = 1.0f / fmaxf((float)(neA - nsA), 1.0f);
                    unsigned ua = (unsigned)sv, ub = (unsigned)(sv >> 32);
                    unsigned o0 = pack_bf2(s0 * inv + bf_lo(ua), s1 * inv + bf_hi(ua));
                    unsigned o1 = pack_bf2(s2 * inv + bf_lo(ub), s3 * inv + bf_hi(ub));
                    *(unsigned long long*)&Ht[row * HSTR + c * 4] =
                        ((unsigned long long)o1 << 32) | o0;
                }
            } else if (half == 0) {
                *(unsigned long long*)&Ht[row * HSTR + c * 4] = 0ull;
            }
            nsA = nsB; neA = neB; idxA = idxB;
            nsB = nsC; neB = neC;
        }
    }
    __syncthreads();

    // ---------- Phase B: MFMA on the 32-row tile ----------
    const int quad = lane >> 4;
    const int r16  = lane & 15;

    if (MODE == 0) {
        // 32 x F_OUT(=128): 2 row-groups x 8 col-groups = 16 tiles, 2 per wave
        const int rowg = wv & 1;
        const int cg0  = (wv >> 1) * 2;
        short8 a[KC];
#pragma unroll
        for (int c = 0; c < KC; ++c)
            a[c] = *(const short8*)&Ht[(16 * rowg + r16) * HSTR + 32 * c + quad * 8];

        floatx4 acc[2];
#pragma unroll
        for (int j = 0; j < 2; ++j)
#pragma unroll
            for (int r = 0; r < 4; ++r) acc[j][r] = 0.f;

#pragma unroll
        for (int j = 0; j < 2; ++j)
#pragma unroll
            for (int c = 0; c < KC; ++c) {
                short8 b = *(const short8*)&Wb[(size_t)(16 * (cg0 + j) + r16) * F_IN + 32 * c + quad * 8];
                acc[j] = __builtin_amdgcn_mfma_f32_16x16x32_bf16(a[c], b, acc[j], 0, 0, 0);
            }

#pragma unroll
        for (int r = 0; r < 4; ++r) {
            const int mm = m0 + 16 * rowg + quad * 4 + r;
            if (mm >= n) continue;
#pragma unroll
            for (int j = 0; j < 2; ++j) {
                const int o = 16 * (cg0 + j) + r16;
                Yb[(size_t)mm * F_OUT + o] = f2bf_rne(fmaxf(acc[j][r] + bias[o], 0.f));
            }
        }
    } else {
        // layer3: 32 x 64 = 2 x 4 tiles, 1 per wave; then heads from LDS Ytile
        const int rowg = wv & 1;
        const int cg   = wv >> 1;      // 0..3
        short8 a[KC];
#pragma unroll
        for (int c = 0; c < KC; ++c)
            a[c] = *(const short8*)&Ht[(16 * rowg + r16) * HSTR + 32 * c + quad * 8];

        floatx4 acc;
#pragma unroll
        for (int r = 0; r < 4; ++r) acc[r] = 0.f;

#pragma unroll
        for (int c = 0; c < KC; ++c) {
            short8 b = *(const short8*)&Wb[(size_t)(16 * cg + r16) * F_IN + 32 * c + quad * 8];
            acc = __builtin_amdgcn_mfma_f32_16x16x32_bf16(a[c], b, acc, 0, 0, 0);
        }

#pragma unroll
        for (int r = 0; r < 4; ++r) {
            const int lr = 16 * rowg + quad * 4 + r;
            const int mm = m0 + lr;
            const int o  = 16 * cg + r16;
            if (mm < n) {
                float v = fmaxf(acc[r] + bias[o], 0.f);
                Yf[(size_t)mm * 64 + o] = v;
                Yt[lr * 72 + o] = f2bf_rne(v);
            } else {
                Yt[lr * 72 + o] = 0;
            }
        }
        __syncthreads();

        // heads: 32 x 80 = 2 x 5 tiles = 10, waves 0..7 take t=wv, waves 0..1 also t=8+wv
        for (int t = wv; t < 10; t += 8) {
            const int rg  = t & 1;
            const int cg2 = t >> 1;    // 0..4
            short8 a2[2];
#pragma unroll
            for (int c = 0; c < 2; ++c)
                a2[c] = *(const short8*)&Yt[(16 * rg + r16) * 72 + 32 * c + quad * 8];

            floatx4 acc2;
#pragma unroll
            for (int r = 0; r < 4; ++r) acc2[r] = 0.f;

#pragma unroll
            for (int c = 0; c < 2; ++c) {
                short8 b = *(const short8*)&Whb[(size_t)(16 * cg2 + r16) * 64 + 32 * c + quad * 8];
                acc2 = __builtin_amdgcn_mfma_f32_16x16x32_bf16(a2[c], b, acc2, 0, 0, 0);
            }

#pragma unroll
            for (int r = 0; r < 4; ++r) {
                const int mm = m0 + 16 * rg + quad * 4 + r;
                if (mm >= n) continue;
                const int o = 16 * cg2 + r16;
                float v = acc2[r] + hbias[o];
                if (o < 64)      nev[(size_t)mm * 64 + o] = v;
                else if (o < 74) cls[(size_t)mm * 10 + (o - 64)] = v;
            }
        }
    }
}

// ---------------- launch ----------------

extern "C" void kernel_launch(void* const* d_in, const int* in_sizes, int n_in,
                              void* d_out, int out_size, void* d_ws, size_t ws_size,
                              hipStream_t stream) {
    const float* x  = (const float*)d_in[0];
    const int*   ei = (const int*)d_in[1];
    const float* W1 = (const float*)d_in[2];
    const float* b1 = (const float*)d_in[3];
    const float* W2 = (const float*)d_in[4];
    const float* b2 = (const float*)d_in[5];
    const float* W3 = (const float*)d_in[6];
    const float* b3 = (const float*)d_in[7];
    const float* Wp = (const float*)d_in[8];
    const float* bp = (const float*)d_in[9];
    const float* Wc = (const float*)d_in[10];
    const float* bc = (const float*)d_in[11];

    const int n = in_sizes[0] / 64;   // 50000
    const int E = in_sizes[1] / 2;    // 800000
    const int* src = ei;
    const int* dst = ei + E;

    const int nScanBlocks = (n + 255) / 256;   // 196

    // workspace layout
    int* deg       = (int*)d_ws;              // n
    int* offsets   = deg + n;                 // n+1
    int* cursor    = offsets + (n + 1);       // n
    int* partial   = cursor + n;              // 256
    unsigned short* csr_src = (unsigned short*)(partial + 256);   // E u16
    uintptr_t p = (uintptr_t)(csr_src + E);
    p = (p + 255) & ~(uintptr_t)255;
    unsigned int* Hb  = (unsigned int*)p;          // n*64 (n x 128 bf16)
    unsigned int* Yb  = Hb + (size_t)n * 64;       // n*64 (n x 128 bf16)
    unsigned int* xb  = Yb + (size_t)n * 64;       // n*32 (n x 64 bf16)
    unsigned int* W1b = xb + (size_t)n * 32;       // 4096 uints
    unsigned int* W2b = W1b + 4096;                // 8192
    unsigned int* W3b = W2b + 8192;                // 4096
    unsigned int* Whb = W3b + 4096;                // 2560
    float* hbias = (float*)(Whb + 2560);           // 80

    float* out_emb = (float*)d_out;
    float* out_nev = out_emb + (size_t)n * 64;
    float* out_cls = out_nev + (size_t)n * 64;

    hipMemsetAsync(deg, 0, (size_t)n * sizeof(int), stream);

    const int nCnt = 256;
    const int convTotal = n * 32 + 4096 + 8192 + 4096 + 2560 + 80;
    const int convBlocks = (convTotal + 255) / 256;
    prep_kernel<<<nCnt + convBlocks, 256, 0, stream>>>(
        dst, deg, E, nCnt,
        x, W1, W2, W3, Wp, bp, Wc, bc, xb, W1b, W2b, W3b, Whb, hbias, n * 32);

    partial_sum_kernel<<<nScanBlocks, 256, 0, stream>>>(deg, partial, n);
    local_scan_kernel<<<nScanBlocks, 256, 0, stream>>>(deg, partial, offsets, cursor, nScanBlocks, n);

    const int nSub = 128;   // 8 shards x 128 subs = 1024 blocks
    scatter_kernel<<<8 * nSub, 256, 0, stream>>>(src, dst, cursor, csr_src, E, nSub);

    const int gF = (n + 31) / 32;    // 1563 blocks, 512 threads

    // layer 1: agg(x, F=64) + GEMM 64->128 -> Hb (bf16)
    fused_agg_gemm_kernel<64, 128, 0><<<gF, 512, 0, stream>>>(
        (const unsigned long long*)xb, offsets, csr_src,
        (const unsigned short*)W1b, b1, (unsigned short*)Hb,
        nullptr, nullptr, nullptr, nullptr, nullptr, n);

    // layer 2: agg(Hb, F=128) + GEMM 128->128 -> Yb (bf16)
    fused_agg_gemm_kernel<128, 128, 0><<<gF, 512, 0, stream>>>(
        (const unsigned long long*)Hb, offsets, csr_src,
        (const unsigned short*)W2b, b2, (unsigned short*)Yb,
        nullptr, nullptr, nullptr, nullptr, nullptr, n);

    // layer 3: agg(Yb, F=128) + GEMM 128->64 + heads -> out_emb / nev / cls
    fused_agg_gemm_kernel<128, 64, 3><<<gF, 512, 0, stream>>>(
        (const unsigned long long*)Yb, offsets, csr_src,
        (const unsigned short*)W3b, b3, nullptr,
        out_emb, out_nev, out_cls, (const unsigned short*)Whb, hbias, n);
}

// Round 7
// 254.170 us; speedup vs baseline: 1.2342x; 1.1204x over previous
//
#include <hip/hip_runtime.h>
#include <hip/hip_bf16.h>

typedef __attribute__((ext_vector_type(8))) short short8;
typedef __attribute__((ext_vector_type(4))) float floatx4;

__device__ __forceinline__ float bf_lo(unsigned int u) { return __uint_as_float(u << 16); }
__device__ __forceinline__ float bf_hi(unsigned int u) { return __uint_as_float(u & 0xffff0000u); }

__device__ __forceinline__ unsigned short f2bf_rne(float f) {
    unsigned u = __float_as_uint(f);
    unsigned rb = (u >> 16) & 1u;
    u += 0x7fffu + rb;
    return (unsigned short)(u >> 16);
}
__device__ __forceinline__ unsigned int pack_bf2(float x, float y) {
    return (unsigned int)f2bf_rne(x) | ((unsigned int)f2bf_rne(y) << 16);
}

__device__ __forceinline__ void acc4(unsigned long long v, float& f0, float& f1, float& f2, float& f3) {
    unsigned ua = (unsigned)v, ub = (unsigned)(v >> 32);
    f0 += bf_lo(ua); f1 += bf_hi(ua); f2 += bf_lo(ub); f3 += bf_hi(ub);
}

// ---------------- prep: deg-count + per-edge rank (blocks [0,nCnt)) + convert/pack (rest) ----------------
// deg pre-zeroed by memset. The counting atomicAdd's RETURN VALUE is each edge's rank
// among same-dst edges -> stored to rnk[] so the scatter needs no atomics at all.

__global__ __launch_bounds__(256) void prep_kernel(const int* __restrict__ dst,
                                                   int* __restrict__ deg,
                                                   unsigned short* __restrict__ rnk,
                                                   int E, int nCnt,
                                                   const float* __restrict__ x,
                                                   const float* __restrict__ W1,
                                                   const float* __restrict__ W2,
                                                   const float* __restrict__ W3,
                                                   const float* __restrict__ Wp, const float* __restrict__ bp,
                                                   const float* __restrict__ Wc, const float* __restrict__ bc,
                                                   unsigned int* __restrict__ xb,
                                                   unsigned int* __restrict__ W1b,
                                                   unsigned int* __restrict__ W2b,
                                                   unsigned int* __restrict__ W3b,
                                                   unsigned int* __restrict__ Whb,
                                                   float* __restrict__ hbias,
                                                   int nx) {
    if ((int)blockIdx.x < nCnt) {
        const int chunk = (E + nCnt - 1) / nCnt;
        const int lo = blockIdx.x * chunk;
        const int hi = min(lo + chunk, E);
        for (int e = lo + threadIdx.x; e < hi; e += 256) {
            int r = atomicAdd(&deg[dst[e]], 1);
            rnk[e] = (unsigned short)r;     // max deg ~50 << 65536
        }
        return;
    }
    int i = (blockIdx.x - nCnt) * 256 + threadIdx.x;
    const int T0 = nx;            // x pairs
    const int T1 = T0 + 4096;     // W1 128x64
    const int T2 = T1 + 8192;     // W2 128x128
    const int T3 = T2 + 4096;     // W3 64x128
    const int T4 = T3 + 2560;     // Whb 80x64
    const int T5 = T4 + 80;       // hbias
    if (i < T0) {
        float2 f = ((const float2*)x)[i];
        xb[i] = pack_bf2(f.x, f.y);
    } else if (i < T1) {
        float2 f = ((const float2*)W1)[i - T0];
        W1b[i - T0] = pack_bf2(f.x, f.y);
    } else if (i < T2) {
        float2 f = ((const float2*)W2)[i - T1];
        W2b[i - T1] = pack_bf2(f.x, f.y);
    } else if (i < T3) {
        float2 f = ((const float2*)W3)[i - T2];
        W3b[i - T2] = pack_bf2(f.x, f.y);
    } else if (i < T4) {
        int j = i - T3;
        int r = j >> 5, c = (j & 31) * 2;
        float v0 = 0.f, v1 = 0.f;
        if (r < 64)      { v0 = Wp[r * 64 + c]; v1 = Wp[r * 64 + c + 1]; }
        else if (r < 74) { v0 = Wc[(r - 64) * 64 + c]; v1 = Wc[(r - 64) * 64 + c + 1]; }
        Whb[j] = pack_bf2(v0, v1);
    } else if (i < T5) {
        int j = i - T4;
        float v = 0.f;
        if (j < 64)      v = bp[j];
        else if (j < 74) v = bc[j - 64];
        hbias[j] = v;
    }
}

// atomic-free scatter: pos = offsets[dst] + precomputed rank. Pure streaming.
__global__ __launch_bounds__(256) void scatter_kernel(const int* __restrict__ src,
                                                      const int* __restrict__ dst,
                                                      const unsigned short* __restrict__ rnk,
                                                      const int* __restrict__ offsets,
                                                      unsigned short* __restrict__ csr_src, int E) {
    const int stride = gridDim.x * 256;
    for (int i = blockIdx.x * 256 + threadIdx.x; i < E; i += stride) {
        int d = dst[i];
        csr_src[offsets[d] + rnk[i]] = (unsigned short)src[i];
    }
}

// ---------------- scan ----------------

__global__ __launch_bounds__(256) void partial_sum_kernel(const int* __restrict__ deg,
                                                          int* __restrict__ partial, int n) {
    __shared__ int s[256];
    int t = threadIdx.x;
    int i = blockIdx.x * 256 + t;
    s[t] = (i < n) ? deg[i] : 0;
    __syncthreads();
    for (int off = 128; off > 0; off >>= 1) {
        if (t < off) s[t] += s[t + off];
        __syncthreads();
    }
    if (t == 0) partial[blockIdx.x] = s[0];
}

__global__ __launch_bounds__(256) void local_scan_kernel(const int* __restrict__ deg,
                                                         const int* __restrict__ partial,
                                                         int* __restrict__ offsets,
                                                         int nblocks, int n) {
    __shared__ int sp[256];
    __shared__ int s[256];
    int t = threadIdx.x;
    sp[t] = (t < nblocks) ? partial[t] : 0;
    __syncthreads();
    for (int off = 1; off < 256; off <<= 1) {
        int u = (t >= off) ? sp[t - off] : 0;
        __syncthreads();
        sp[t] += u;
        __syncthreads();
    }
    const int blockbase = (blockIdx.x == 0) ? 0 : sp[blockIdx.x - 1];
    if (blockIdx.x == 0 && t == 0) offsets[n] = sp[nblocks - 1];

    int i = blockIdx.x * 256 + t;
    int v = (i < n) ? deg[i] : 0;
    s[t] = v;
    __syncthreads();
    for (int off = 1; off < 256; off <<= 1) {
        int u = (t >= off) ? s[t - off] : 0;
        __syncthreads();
        s[t] += u;
        __syncthreads();
    }
    if (i < n) offsets[i] = blockbase + s[t] - v;
}

// ---------------- Fused agg + MFMA GEMM per layer ----------------
// Block = 512 threads (8 waves), 32 nodes. Phase A: one node per LANE GROUP —
// F=64: 4 nodes/wave (16-lane groups), F=128: 2 nodes/pass (32-lane halves, 2
// passes). Uniform stripe loop (16 edges/stripe) with v[16] batches -> 16 load
// instructions (8KB) in flight per wave, serial phase count 4 -> 1 (F=64) / 2
// (F=128). Per-node edge accumulation strictly sequential; no cross-lane reduce.
// csr stripe k+1 prefetched before stripe k's gathers. The stripe loop bound mc
// is wave-uniform (shfl-max over all groups), so all __shfl sources are active.
// Phase B: 8 waves MFMA the 32xF_OUT tile from LDS.
// MODE 0: bf16 out + relu.  MODE 3: relu, fp32 emb out, heads MFMA via LDS Ytile.

template <int F_IN, int F_OUT, int MODE>
__global__ __launch_bounds__(512) void fused_agg_gemm_kernel(
        const unsigned long long* __restrict__ xt,      // gather table, F_IN/4 u64 per row
        const int* __restrict__ offsets,
        const unsigned short* __restrict__ csr_src,
        const unsigned short* __restrict__ Wb,          // F_OUT x F_IN bf16
        const float* __restrict__ bias,
        unsigned short* __restrict__ Yb,                // MODE 0 out
        float* __restrict__ Yf,                         // MODE 3: emb out (fp32)
        float* __restrict__ nev, float* __restrict__ cls,
        const unsigned short* __restrict__ Whb, const float* __restrict__ hbias,
        int n) {
    constexpr int KC   = F_IN / 32;     // short8 chunks per row
    constexpr int XSTR = F_IN / 4;      // u64 per gather-table row
    constexpr int HSTR = F_IN + 8;      // LDS row stride (shorts), breaks pow2 banks
    __shared__ __align__(16) unsigned short Ht[32 * HSTR];
    __shared__ __align__(16) unsigned short Yt[(MODE == 3) ? 32 * 72 : 16];

    const int lane = threadIdx.x & 63;
    const int wv   = threadIdx.x >> 6;      // 0..7
    const int m0   = blockIdx.x * 32;

    // ---------- Phase A ----------
    if (F_IN == 64) {
        const int g   = lane >> 4;          // node group 0..3
        const int c   = lane & 15;          // u64 col within row
        const int row = wv * 4 + g;
        const int node = m0 + row;
        int ns = 0, ne = 0;
        if (node < n) { ns = offsets[node]; ne = offsets[node + 1]; }
        const int cnt = ne - ns;
        unsigned long long sv = (node < n) ? xt[(size_t)node * XSTR + c] : 0ull;

        int mc = cnt;
        mc = max(mc, __shfl(mc, lane ^ 16, 64));
        mc = max(mc, __shfl(mc, lane ^ 32, 64));    // wave-max edge count

        float s0 = 0.f, s1 = 0.f, s2 = 0.f, s3 = 0.f;
        int ii0 = ns + c;
        if (cnt > 0) { if (ii0 >= ne) ii0 = ne - 1; } else ii0 = 0;
        int idx = (mc > 0) ? (int)csr_src[ii0] : 0;

        for (int base = 0; base < mc; base += 16) {
            int idxN = 0;                            // prefetch next stripe's csr
            if (base + 16 < mc) {
                int ii = ns + base + 16 + c;
                if (cnt > 0) { if (ii >= ne) ii = ne - 1; } else ii = 0;
                idxN = csr_src[ii];
            }
            unsigned long long v[16];
#pragma unroll
            for (int q = 0; q < 16; ++q) {
                int nb = __shfl(idx, g * 16 + q, 64);   // all lanes execute
                if (base + q < cnt) v[q] = xt[(size_t)nb * XSTR + c];
            }
#pragma unroll
            for (int q = 0; q < 16; ++q)
                if (base + q < cnt) acc4(v[q], s0, s1, s2, s3);
            idx = idxN;
        }
        float inv = 1.0f / fmaxf((float)cnt, 1.0f);
        unsigned ua = (unsigned)sv, ub = (unsigned)(sv >> 32);
        unsigned o0 = pack_bf2(s0 * inv + bf_lo(ua), s1 * inv + bf_hi(ua));
        unsigned o1 = pack_bf2(s2 * inv + bf_lo(ub), s3 * inv + bf_hi(ub));
        *(unsigned long long*)&Ht[row * HSTR + c * 4] =
            ((unsigned long long)o1 << 32) | o0;
    } else {
        const int g = lane >> 5;            // half 0..1
        const int c = lane & 31;            // u64 col within row
        const int row0 = wv * 4 + g;
        const int row1 = wv * 4 + 2 + g;
        const int node0 = m0 + row0, node1 = m0 + row1;
        int ns0 = 0, ne0 = 0, ns1 = 0, ne1 = 0;
        if (node0 < n) { ns0 = offsets[node0]; ne0 = offsets[node0 + 1]; }
        if (node1 < n) { ns1 = offsets[node1]; ne1 = offsets[node1 + 1]; }
        const int cnt0 = ne0 - ns0, cnt1 = ne1 - ns1;
        unsigned long long sv0 = (node0 < n) ? xt[(size_t)node0 * XSTR + c] : 0ull;
        unsigned long long sv1 = (node1 < n) ? xt[(size_t)node1 * XSTR + c] : 0ull;
        int mc0 = max(cnt0, __shfl(cnt0, lane ^ 32, 64));
        int mc1 = max(cnt1, __shfl(cnt1, lane ^ 32, 64));
        // prefetch first csr stripes for both passes (issued back-to-back)
        int iiA = ns0 + (c & 15);
        if (cnt0 > 0) { if (iiA >= ne0) iiA = ne0 - 1; } else iiA = 0;
        int iiB = ns1 + (c & 15);
        if (cnt1 > 0) { if (iiB >= ne1) iiB = ne1 - 1; } else iiB = 0;
        int idx0 = (mc0 > 0) ? (int)csr_src[iiA] : 0;
        int idx1 = (mc1 > 0) ? (int)csr_src[iiB] : 0;

        // pass 0: nodes row0 (both halves)
        {
            float s0 = 0.f, s1 = 0.f, s2 = 0.f, s3 = 0.f;
            int idx = idx0;
            for (int base = 0; base < mc0; base += 16) {
                int idxN = 0;
                if (base + 16 < mc0) {
                    int ii = ns0 + base + 16 + (c & 15);
                    if (cnt0 > 0) { if (ii >= ne0) ii = ne0 - 1; } else ii = 0;
                    idxN = csr_src[ii];
                }
                unsigned long long v[16];
#pragma unroll
                for (int q = 0; q < 16; ++q) {
                    int nb = __shfl(idx, g * 32 + q, 64);
                    if (base + q < cnt0) v[q] = xt[(size_t)nb * XSTR + c];
                }
#pragma unroll
                for (int q = 0; q < 16; ++q)
                    if (base + q < cnt0) acc4(v[q], s0, s1, s2, s3);
                idx = idxN;
            }
            float inv = 1.0f / fmaxf((float)cnt0, 1.0f);
            unsigned ua = (unsigned)sv0, ub = (unsigned)(sv0 >> 32);
            unsigned o0 = pack_bf2(s0 * inv + bf_lo(ua), s1 * inv + bf_hi(ua));
            unsigned o1 = pack_bf2(s2 * inv + bf_lo(ub), s3 * inv + bf_hi(ub));
            *(unsigned long long*)&Ht[row0 * HSTR + c * 4] =
                ((unsigned long long)o1 << 32) | o0;
        }
        // pass 1: nodes row1 (both halves)
        {
            float s0 = 0.f, s1 = 0.f, s2 = 0.f, s3 = 0.f;
            int idx = idx1;
            for (int base = 0; base < mc1; base += 16) {
                int idxN = 0;
                if (base + 16 < mc1) {
                    int ii = ns1 + base + 16 + (c & 15);
                    if (cnt1 > 0) { if (ii >= ne1) ii = ne1 - 1; } else ii = 0;
                    idxN = csr_src[ii];
                }
                unsigned long long v[16];
#pragma unroll
                for (int q = 0; q < 16; ++q) {
                    int nb = __shfl(idx, g * 32 + q, 64);
                    if (base + q < cnt1) v[q] = xt[(size_t)nb * XSTR + c];
                }
#pragma unroll
                for (int q = 0; q < 16; ++q)
                    if (base + q < cnt1) acc4(v[q], s0, s1, s2, s3);
                idx = idxN;
            }
            float inv = 1.0f / fmaxf((float)cnt1, 1.0f);
            unsigned ua = (unsigned)sv1, ub = (unsigned)(sv1 >> 32);
            unsigned o0 = pack_bf2(s0 * inv + bf_lo(ua), s1 * inv + bf_hi(ua));
            unsigned o1 = pack_bf2(s2 * inv + bf_lo(ub), s3 * inv + bf_hi(ub));
            *(unsigned long long*)&Ht[row1 * HSTR + c * 4] =
                ((unsigned long long)o1 << 32) | o0;
        }
    }
    __syncthreads();

    // ---------- Phase B: MFMA on the 32-row tile ----------
    const int quad = lane >> 4;
    const int r16  = lane & 15;

    if (MODE == 0) {
        // 32 x F_OUT(=128): 2 row-groups x 8 col-groups = 16 tiles, 2 per wave
        const int rowg = wv & 1;
        const int cg0  = (wv >> 1) * 2;
        short8 a[KC];
#pragma unroll
        for (int c = 0; c < KC; ++c)
            a[c] = *(const short8*)&Ht[(16 * rowg + r16) * HSTR + 32 * c + quad * 8];

        floatx4 acc[2];
#pragma unroll
        for (int j = 0; j < 2; ++j)
#pragma unroll
            for (int r = 0; r < 4; ++r) acc[j][r] = 0.f;

#pragma unroll
        for (int j = 0; j < 2; ++j)
#pragma unroll
            for (int c = 0; c < KC; ++c) {
                short8 b = *(const short8*)&Wb[(size_t)(16 * (cg0 + j) + r16) * F_IN + 32 * c + quad * 8];
                acc[j] = __builtin_amdgcn_mfma_f32_16x16x32_bf16(a[c], b, acc[j], 0, 0, 0);
            }

#pragma unroll
        for (int r = 0; r < 4; ++r) {
            const int mm = m0 + 16 * rowg + quad * 4 + r;
            if (mm >= n) continue;
#pragma unroll
            for (int j = 0; j < 2; ++j) {
                const int o = 16 * (cg0 + j) + r16;
                Yb[(size_t)mm * F_OUT + o] = f2bf_rne(fmaxf(acc[j][r] + bias[o], 0.f));
            }
        }
    } else {
        // layer3: 32 x 64 = 2 x 4 tiles, 1 per wave; then heads from LDS Ytile
        const int rowg = wv & 1;
        const int cg   = wv >> 1;      // 0..3
        short8 a[KC];
#pragma unroll
        for (int c = 0; c < KC; ++c)
            a[c] = *(const short8*)&Ht[(16 * rowg + r16) * HSTR + 32 * c + quad * 8];

        floatx4 acc;
#pragma unroll
        for (int r = 0; r < 4; ++r) acc[r] = 0.f;

#pragma unroll
        for (int c = 0; c < KC; ++c) {
            short8 b = *(const short8*)&Wb[(size_t)(16 * cg + r16) * F_IN + 32 * c + quad * 8];
            acc = __builtin_amdgcn_mfma_f32_16x16x32_bf16(a[c], b, acc, 0, 0, 0);
        }

#pragma unroll
        for (int r = 0; r < 4; ++r) {
            const int lr = 16 * rowg + quad * 4 + r;
            const int mm = m0 + lr;
            const int o  = 16 * cg + r16;
            if (mm < n) {
                float v = fmaxf(acc[r] + bias[o], 0.f);
                Yf[(size_t)mm * 64 + o] = v;
                Yt[lr * 72 + o] = f2bf_rne(v);
            } else {
                Yt[lr * 72 + o] = 0;
            }
        }
        __syncthreads();

        // heads: 32 x 80 = 2 x 5 tiles = 10, waves 0..7 take t=wv, waves 0..1 also t=8+wv
        for (int t = wv; t < 10; t += 8) {
            const int rg  = t & 1;
            const int cg2 = t >> 1;    // 0..4
            short8 a2[2];
#pragma unroll
            for (int c = 0; c < 2; ++c)
                a2[c] = *(const short8*)&Yt[(16 * rg + r16) * 72 + 32 * c + quad * 8];

            floatx4 acc2;
#pragma unroll
            for (int r = 0; r < 4; ++r) acc2[r] = 0.f;

#pragma unroll
            for (int c = 0; c < 2; ++c) {
                short8 b = *(const short8*)&Whb[(size_t)(16 * cg2 + r16) * 64 + 32 * c + quad * 8];
                acc2 = __builtin_amdgcn_mfma_f32_16x16x32_bf16(a2[c], b, acc2, 0, 0, 0);
            }

#pragma unroll
            for (int r = 0; r < 4; ++r) {
                const int mm = m0 + 16 * rg + quad * 4 + r;
                if (mm >= n) continue;
                const int o = 16 * cg2 + r16;
                float v = acc2[r] + hbias[o];
                if (o < 64)      nev[(size_t)mm * 64 + o] = v;
                else if (o < 74) cls[(size_t)mm * 10 + (o - 64)] = v;
            }
        }
    }
}

// ---------------- launch ----------------

extern "C" void kernel_launch(void* const* d_in, const int* in_sizes, int n_in,
                              void* d_out, int out_size, void* d_ws, size_t ws_size,
                              hipStream_t stream) {
    const float* x  = (const float*)d_in[0];
    const int*   ei = (const int*)d_in[1];
    const float* W1 = (const float*)d_in[2];
    const float* b1 = (const float*)d_in[3];
    const float* W2 = (const float*)d_in[4];
    const float* b2 = (const float*)d_in[5];
    const float* W3 = (const float*)d_in[6];
    const float* b3 = (const float*)d_in[7];
    const float* Wp = (const float*)d_in[8];
    const float* bp = (const float*)d_in[9];
    const float* Wc = (const float*)d_in[10];
    const float* bc = (const float*)d_in[11];

    const int n = in_sizes[0] / 64;   // 50000
    const int E = in_sizes[1] / 2;    // 800000
    const int* src = ei;
    const int* dst = ei + E;

    const int nScanBlocks = (n + 255) / 256;   // 196

    // workspace layout
    int* deg       = (int*)d_ws;              // n
    int* offsets   = deg + n;                 // n+1
    int* partial   = offsets + (n + 1);       // 256
    unsigned short* rnk     = (unsigned short*)(partial + 256);   // E u16
    unsigned short* csr_src = rnk + E;                            // E u16
    uintptr_t p = (uintptr_t)(csr_src + E);
    p = (p + 255) & ~(uintptr_t)255;
    unsigned int* Hb  = (unsigned int*)p;          // n*64 (n x 128 bf16)
    unsigned int* Yb  = Hb + (size_t)n * 64;       // n*64 (n x 128 bf16)
    unsigned int* xb  = Yb + (size_t)n * 64;       // n*32 (n x 64 bf16)
    unsigned int* W1b = xb + (size_t)n * 32;       // 4096 uints
    unsigned int* W2b = W1b + 4096;                // 8192
    unsigned int* W3b = W2b + 8192;                // 4096
    unsigned int* Whb = W3b + 4096;                // 2560
    float* hbias = (float*)(Whb + 2560);           // 80

    float* out_emb = (float*)d_out;
    float* out_nev = out_emb + (size_t)n * 64;
    float* out_cls = out_nev + (size_t)n * 64;

    hipMemsetAsync(deg, 0, (size_t)n * sizeof(int), stream);

    const int nCnt = 256;
    const int convTotal = n * 32 + 4096 + 8192 + 4096 + 2560 + 80;
    const int convBlocks = (convTotal + 255) / 256;
    prep_kernel<<<nCnt + convBlocks, 256, 0, stream>>>(
        dst, deg, rnk, E, nCnt,
        x, W1, W2, W3, Wp, bp, Wc, bc, xb, W1b, W2b, W3b, Whb, hbias, n * 32);

    partial_sum_kernel<<<nScanBlocks, 256, 0, stream>>>(deg, partial, n);
    local_scan_kernel<<<nScanBlocks, 256, 0, stream>>>(deg, partial, offsets, nScanBlocks, n);

    scatter_kernel<<<1024, 256, 0, stream>>>(src, dst, rnk, offsets, csr_src, E);

    const int gF = (n + 31) / 32;    // 1563 blocks, 512 threads

    // layer 1: agg(x, F=64) + GEMM 64->128 -> Hb (bf16)
    fused_agg_gemm_kernel<64, 128, 0><<<gF, 512, 0, stream>>>(
        (const unsigned long long*)xb, offsets, csr_src,
        (const unsigned short*)W1b, b1, (unsigned short*)Hb,
        nullptr, nullptr, nullptr, nullptr, nullptr, n);

    // layer 2: agg(Hb, F=128) + GEMM 128->128 -> Yb (bf16)
    fused_agg_gemm_kernel<128, 128, 0><<<gF, 512, 0, stream>>>(
        (const unsigned long long*)Hb, offsets, csr_src,
        (const unsigned short*)W2b, b2, (unsigned short*)Yb,
        nullptr, nullptr, nullptr, nullptr, nullptr, n);

    // layer 3: agg(Yb, F=128) + GEMM 128->64 + heads -> out_emb / nev / cls
    fused_agg_gemm_kernel<128, 64, 3><<<gF, 512, 0, stream>>>(
        (const unsigned long long*)Yb, offsets, csr_src,
        (const unsigned short*)W3b, b3, nullptr,
        out_emb, out_nev, out_cls, (const unsigned short*)Whb, hbias, n);
}